// Round 1
// baseline (1232.063 us; speedup 1.0000x reference)
//
#include <hip/hip_runtime.h>
#include <cstdint>
#include <cstddef>

typedef __bf16 bf16x8 __attribute__((ext_vector_type(8)));
typedef __bf16 bf16x4 __attribute__((ext_vector_type(4)));
typedef float  f32x4  __attribute__((ext_vector_type(4)));

#define DMODEL 256

__device__ __forceinline__ float bflo(unsigned u) { return __builtin_bit_cast(float, u << 16); }
__device__ __forceinline__ float bfhi(unsigned u) { return __builtin_bit_cast(float, u & 0xffff0000u); }

// ---------------- weight transpose + f32->bf16 convert ----------------
__global__ void transpose_cvt(const float* __restrict__ in, __bf16* __restrict__ out, int R, int C) {
  int i = blockIdx.x * 256 + threadIdx.x;
  if (i >= R * C) return;
  int r = i / C, c = i - r * C;
  out[(size_t)c * R + r] = (__bf16)in[i];
}

// ---------------- embedding gather ----------------
__global__ void embed_k(const int* __restrict__ ids, const float* __restrict__ emb, float* __restrict__ x) {
  int row = blockIdx.x * 4 + (threadIdx.x >> 6);
  int lane = threadIdx.x & 63;
  int id = ids[row];
  ((f32x4*)(x + (size_t)row * DMODEL))[lane] = ((const f32x4*)(emb + (size_t)id * DMODEL))[lane];
}

// ---------------- rmsnorm (one wave per row of 256) ----------------
template<typename OUT>
__global__ void rmsnorm_k(const float* __restrict__ x, const float* __restrict__ w, OUT* __restrict__ out) {
  int row = blockIdx.x * 4 + (threadIdx.x >> 6);
  int lane = threadIdx.x & 63;
  f32x4 v = ((const f32x4*)(x + (size_t)row * DMODEL))[lane];
  float ss = v[0]*v[0] + v[1]*v[1] + v[2]*v[2] + v[3]*v[3];
  #pragma unroll
  for (int off = 1; off < 64; off <<= 1) ss += __shfl_xor(ss, off);
  float rms = rsqrtf(ss * (1.0f / DMODEL) + 1e-8f);
  f32x4 wv = ((const f32x4*)w)[lane];
  if constexpr (sizeof(OUT) == 4) {
    f32x4 o;
    o[0] = v[0]*rms*wv[0]; o[1] = v[1]*rms*wv[1]; o[2] = v[2]*rms*wv[2]; o[3] = v[3]*rms*wv[3];
    ((f32x4*)((float*)out + (size_t)row * DMODEL))[lane] = o;
  } else {
    bf16x4 o;
    o[0] = (__bf16)(v[0]*rms*wv[0]); o[1] = (__bf16)(v[1]*rms*wv[1]);
    o[2] = (__bf16)(v[2]*rms*wv[2]); o[3] = (__bf16)(v[3]*rms*wv[3]);
    ((bf16x4*)((__bf16*)out + (size_t)row * DMODEL))[lane] = o;
  }
}

// ---------------- gelu (tanh approx, matches jax.nn.gelu default) ----------------
__device__ __forceinline__ float gelu_f(float v) {
  return 0.5f * v * (1.0f + tanhf(0.7978845608028654f * (v + 0.044715f * v * v * v)));
}

// ---------------- bf16 MFMA GEMM: C(MxN) = A(MxK) @ Bt(NxK)^T ----------------
// 128x128 block tile, 4 waves each 64x64 (4x4 frags of 16x16x32). Direct global frag loads.
template<bool RES, bool GELU, bool OUTB>
__launch_bounds__(256)
__global__ void gemm_bt(const __bf16* __restrict__ A, const __bf16* __restrict__ Bt,
                        __bf16* __restrict__ outb, float* __restrict__ res,
                        int K, int N) {
  int tid = threadIdx.x;
  int lane = tid & 63;
  int w = tid >> 6;
  int wr = w >> 1, wc = w & 1;
  int lr = lane & 15;
  int lkb = (lane >> 4) << 3;           // 0,8,16,24  (K offset of this lane's 8 contiguous elems)
  size_t bm = (size_t)blockIdx.x * 128, bn = (size_t)blockIdx.y * 128;
  const __bf16* Ap = A + (bm + wr * 64 + lr) * (size_t)K + lkb;
  const __bf16* Bp = Bt + (bn + wc * 64 + lr) * (size_t)K + lkb;
  f32x4 acc[4][4] = {};
  #pragma unroll 2
  for (int kk = 0; kk < K; kk += 32) {
    bf16x8 av[4], bv[4];
    #pragma unroll
    for (int i = 0; i < 4; ++i) av[i] = *(const bf16x8*)(Ap + (size_t)i * 16 * K + kk);
    #pragma unroll
    for (int i = 0; i < 4; ++i) bv[i] = *(const bf16x8*)(Bp + (size_t)i * 16 * K + kk);
    #pragma unroll
    for (int mi = 0; mi < 4; ++mi)
      #pragma unroll
      for (int ni = 0; ni < 4; ++ni)
        acc[mi][ni] = __builtin_amdgcn_mfma_f32_16x16x32_bf16(av[mi], bv[ni], acc[mi][ni], 0, 0, 0);
  }
  // C/D layout: col = lane&15, row = (lane>>4)*4 + reg  [verified m89/m91]
  size_t row0 = bm + wr * 64 + ((lane >> 4) << 2);
  size_t col0 = bn + wc * 64 + lr;
  #pragma unroll
  for (int mi = 0; mi < 4; ++mi)
    #pragma unroll
    for (int ni = 0; ni < 4; ++ni)
      #pragma unroll
      for (int j = 0; j < 4; ++j) {
        size_t row = row0 + mi * 16 + j, col = col0 + ni * 16;
        float val = acc[mi][ni][j];
        if constexpr (GELU) val = gelu_f(val);
        if constexpr (RES)  res[row * N + col] += val;
        if constexpr (OUTB) outb[row * N + col] = (__bf16)val;
      }
}

// ---------------- block-sparse attention ----------------
// grid = B*H*nB = 2048 blocks, 1024 threads. qkv: (16384, 768) bf16 [q|k|v].
// Per block: 64 queries x 448 selected keys x dh=32.
// LDS: sc = f16[64][456] raw scores->exp ; kv = f32[448][36], row s stored at (s%28)*16 + s/28.
#define SC_STR 456
#define KV_STR 36
#define ATTN_LDS (64 * SC_STR * 2 + 448 * KV_STR * 4)   // 58368 + 64512 = 122880 B

__launch_bounds__(1024)
__global__ void attn_k(const __bf16* __restrict__ qkv, const int* __restrict__ rand_idx,
                       __bf16* __restrict__ o) {
  extern __shared__ char smem[];
  _Float16* sc = (_Float16*)smem;
  float* kv = (float*)(smem + 64 * SC_STR * 2);
  int tid = threadIdx.x;
  int bid = blockIdx.x;
  int b = bid >> 8;            // H*nB = 256
  int hh = (bid >> 5) & 7;
  int n = bid & 31;
  int r5 = rand_idx[n * 2], r6 = rand_idx[n * 2 + 1];
  int nm1 = n > 0 ? n - 1 : 0;
  int np1 = n < 31 ? n + 1 : 31;
  size_t base = (size_t)b * 2048;
  int qi = tid >> 4, p = tid & 15;

  // q row (32 dims) -> registers
  float qr[32];
  {
    const unsigned* qsrc = (const unsigned*)(qkv + (base + n * 64 + qi) * 768 + hh * 32);
    #pragma unroll
    for (int c = 0; c < 16; ++c) { unsigned u = qsrc[c]; qr[2*c] = bflo(u); qr[2*c+1] = bfhi(u); }
  }

  // ---- stage K (bf16 global -> f32 LDS, permuted rows) ----
  #pragma unroll
  for (int it = 0; it < 4; ++it) {
    int u = tid + it * 1024;
    if (u < 3584) {
      int r = u >> 3, c = u & 7;
      int m = r >> 6, si = r & 63;
      int kb = m == 0 ? 0 : m == 1 ? 1 : m == 2 ? nm1 : m == 3 ? n : m == 4 ? np1 : m == 5 ? r5 : r6;
      const unsigned* src = (const unsigned*)(qkv + (base + kb * 64 + si) * 768 + 256 + hh * 32 + c * 4);
      unsigned d0 = src[0], d1 = src[1];
      int pp = (r * 37450) >> 20;                 // r / 28 (magic, exact for r<448)
      int lrw = (r - pp * 28) * 16 + pp;
      float* dst = kv + lrw * KV_STR + c * 4;
      dst[0] = bflo(d0); dst[1] = bfhi(d0); dst[2] = bflo(d1); dst[3] = bfhi(d1);
    }
  }
  __syncthreads();

  // ---- scores: thread (qi,p) -> s = p*28 + j ----
  const float scale = 0.17677669529663687f;      // 1/sqrt(32)
  for (int j = 0; j < 28; ++j) {
    const float* krow = kv + (16 * j + p) * KV_STR;
    float s0 = 0, s1 = 0, s2 = 0, s3 = 0;
    #pragma unroll
    for (int c = 0; c < 8; ++c) {
      f32x4 k4 = *(const f32x4*)(krow + c * 4);
      s0 += qr[4*c+0] * k4[0];
      s1 += qr[4*c+1] * k4[1];
      s2 += qr[4*c+2] * k4[2];
      s3 += qr[4*c+3] * k4[3];
    }
    sc[qi * SC_STR + p * 28 + j] = (_Float16)(((s0 + s1) + (s2 + s3)) * scale);
  }
  __syncthreads();

  // ---- softmax over the row's 448 (16-lane group owns one row) ----
  float mx = -1e30f;
  for (int j = 0; j < 28; ++j) mx = fmaxf(mx, (float)sc[qi * SC_STR + p * 28 + j]);
  #pragma unroll
  for (int off = 1; off < 16; off <<= 1) mx = fmaxf(mx, __shfl_xor(mx, off));
  float sum = 0.f;
  for (int j = 0; j < 28; ++j) {
    float e = __expf((float)sc[qi * SC_STR + p * 28 + j] - mx);
    sum += e;
    sc[qi * SC_STR + p * 28 + j] = (_Float16)e;
  }
  #pragma unroll
  for (int off = 1; off < 16; off <<= 1) sum += __shfl_xor(sum, off);
  float inv = 1.0f / sum;

  // ---- stage V (overwrite kv; all scores reads done at barrier above) ----
  #pragma unroll
  for (int it = 0; it < 4; ++it) {
    int u = tid + it * 1024;
    if (u < 3584) {
      int r = u >> 3, c = u & 7;
      int m = r >> 6, si = r & 63;
      int kb = m == 0 ? 0 : m == 1 ? 1 : m == 2 ? nm1 : m == 3 ? n : m == 4 ? np1 : m == 5 ? r5 : r6;
      const unsigned* src = (const unsigned*)(qkv + (base + kb * 64 + si) * 768 + 512 + hh * 32 + c * 4);
      unsigned d0 = src[0], d1 = src[1];
      int pp = (r * 37450) >> 20;
      int lrw = (r - pp * 28) * 16 + pp;
      float* dst = kv + lrw * KV_STR + c * 4;
      dst[0] = bflo(d0); dst[1] = bfhi(d0); dst[2] = bflo(d1); dst[3] = bfhi(d1);
    }
  }
  __syncthreads();

  // ---- PV: thread (qi,p) accumulates its 28 s-rows over all 32 d, then 16-lane reduce ----
  float acc[32];
  #pragma unroll
  for (int d = 0; d < 32; ++d) acc[d] = 0.f;
  for (int j = 0; j < 28; ++j) {
    float a = (float)sc[qi * SC_STR + p * 28 + j];
    const float* vrow = kv + (16 * j + p) * KV_STR;
    #pragma unroll
    for (int c = 0; c < 8; ++c) {
      f32x4 v4 = *(const f32x4*)(vrow + c * 4);
      acc[4*c+0] += a * v4[0];
      acc[4*c+1] += a * v4[1];
      acc[4*c+2] += a * v4[2];
      acc[4*c+3] += a * v4[3];
    }
  }
  #pragma unroll
  for (int d = 0; d < 32; ++d) {
    #pragma unroll
    for (int off = 1; off < 16; off <<= 1) acc[d] += __shfl_xor(acc[d], off);
  }
  float a0 = 0.f, a1 = 0.f;
  #pragma unroll
  for (int d = 0; d < 16; ++d) if (p == d) { a0 = acc[2*d]; a1 = acc[2*d+1]; }  // static idx only
  a0 *= inv; a1 *= inv;
  unsigned short u0 = __builtin_bit_cast(unsigned short, (__bf16)a0);
  unsigned short u1 = __builtin_bit_cast(unsigned short, (__bf16)a1);
  unsigned pack = (unsigned)u0 | ((unsigned)u1 << 16);
  *(unsigned*)(o + (base + n * 64 + qi) * 256 + hh * 32 + p * 2) = pack;
}

// ---------------- launch ----------------
extern "C" void kernel_launch(void* const* d_in, const int* in_sizes, int n_in,
                              void* d_out, int out_size, void* d_ws, size_t ws_size,
                              hipStream_t stream) {
  const int*   ids      = (const int*)d_in[0];
  const int*   rand_idx = (const int*)d_in[1];
  const float* emb      = (const float*)d_in[2];
  const float* ln1      = (const float*)d_in[3];
  const float* wq       = (const float*)d_in[4];
  const float* wk       = (const float*)d_in[5];
  const float* wv       = (const float*)d_in[6];
  const float* wo       = (const float*)d_in[7];
  const float* ln2      = (const float*)d_in[8];
  const float* w1       = (const float*)d_in[9];
  const float* w2       = (const float*)d_in[10];
  const float* fln      = (const float*)d_in[11];
  float* out = (float*)d_out;

  char* ws = (char*)d_ws;
  float*  x    = (float*)ws;                       // 16,777,216 B
  __bf16* h    = (__bf16*)(ws + 16777216);         //  8,388,608 B
  __bf16* qkv  = (__bf16*)(ws + 25165824);         // 25,165,824 B
  __bf16* obuf = (__bf16*)(ws + 50331648);         //  8,388,608 B
  __bf16* g    = qkv;                              // reuses qkv+obuf (33,554,432 B), both dead by FFN
  __bf16* wbase = (__bf16*)(ws + 58720256);        //  3,145,728 B  (total 61.9 MB)

  // weights -> bf16, transposed to (N x K)
  for (int l = 0; l < 2; ++l) {
    __bf16* qkvT = wbase + (size_t)l * 786432;
    __bf16* woT  = qkvT + 196608;
    __bf16* w1T  = woT + 65536;
    __bf16* w2T  = w1T + 262144;
    transpose_cvt<<<256,  256, 0, stream>>>(wq + (size_t)l * 65536, qkvT,          256, 256);
    transpose_cvt<<<256,  256, 0, stream>>>(wk + (size_t)l * 65536, qkvT + 65536,  256, 256);
    transpose_cvt<<<256,  256, 0, stream>>>(wv + (size_t)l * 65536, qkvT + 131072, 256, 256);
    transpose_cvt<<<256,  256, 0, stream>>>(wo + (size_t)l * 65536, woT,           256, 256);
    transpose_cvt<<<1024, 256, 0, stream>>>(w1 + (size_t)l * 262144, w1T,          256, 1024);
    transpose_cvt<<<1024, 256, 0, stream>>>(w2 + (size_t)l * 262144, w2T,          1024, 256);
  }

  embed_k<<<4096, 256, 0, stream>>>(ids, emb, x);

  for (int l = 0; l < 2; ++l) {
    __bf16* qkvT = wbase + (size_t)l * 786432;
    __bf16* woT  = qkvT + 196608;
    __bf16* w1T  = woT + 65536;
    __bf16* w2T  = w1T + 262144;

    rmsnorm_k<__bf16><<<4096, 256, 0, stream>>>(x, ln1 + (size_t)l * 256, h);
    gemm_bt<false, false, true><<<dim3(128, 6), 256, 0, stream>>>(h, qkvT, qkv, nullptr, 256, 768);
    attn_k<<<2048, 1024, ATTN_LDS, stream>>>(qkv, rand_idx, obuf);
    gemm_bt<true, false, false><<<dim3(128, 2), 256, 0, stream>>>(obuf, woT, nullptr, x, 256, 256);
    rmsnorm_k<__bf16><<<4096, 256, 0, stream>>>(x, ln2 + (size_t)l * 256, h);
    gemm_bt<false, true, true><<<dim3(128, 8), 256, 0, stream>>>(h, w1T, g, nullptr, 256, 1024);
    gemm_bt<true, false, false><<<dim3(128, 2), 256, 0, stream>>>(g, w2T, nullptr, x, 1024, 256);
  }

  rmsnorm_k<float><<<4096, 256, 0, stream>>>(x, fln, out);
}

// Round 3
// 610.402 us; speedup vs baseline: 2.0184x; 2.0184x over previous
//
#include <hip/hip_runtime.h>
#include <cstdint>
#include <cstddef>

typedef __bf16 bf16x8 __attribute__((ext_vector_type(8)));
typedef __bf16 bf16x4 __attribute__((ext_vector_type(4)));
typedef float  f32x4  __attribute__((ext_vector_type(4)));
typedef unsigned u32x2 __attribute__((ext_vector_type(2)));
typedef unsigned u32x4 __attribute__((ext_vector_type(4)));

#define DMODEL 256

__device__ __forceinline__ float bflo(unsigned u) { return __builtin_bit_cast(float, u << 16); }
__device__ __forceinline__ float bfhi(unsigned u) { return __builtin_bit_cast(float, u & 0xffff0000u); }
__device__ __forceinline__ unsigned short bfbits(float f) {
  return __builtin_bit_cast(unsigned short, (__bf16)f);
}

// ---------------- weight transpose + f32->bf16 convert ----------------
__global__ void transpose_cvt(const float* __restrict__ in, __bf16* __restrict__ out, int R, int C) {
  int i = blockIdx.x * 256 + threadIdx.x;
  if (i >= R * C) return;
  int r = i / C, c = i - r * C;
  out[(size_t)c * R + r] = (__bf16)in[i];
}

// ---------------- embedding gather ----------------
__global__ void embed_k(const int* __restrict__ ids, const float* __restrict__ emb, float* __restrict__ x) {
  int row = blockIdx.x * 4 + (threadIdx.x >> 6);
  int lane = threadIdx.x & 63;
  int id = ids[row];
  ((f32x4*)(x + (size_t)row * DMODEL))[lane] = ((const f32x4*)(emb + (size_t)id * DMODEL))[lane];
}

// ---------------- rmsnorm (one wave per row of 256) ----------------
template<typename OUT>
__global__ void rmsnorm_k(const float* __restrict__ x, const float* __restrict__ w, OUT* __restrict__ out) {
  int row = blockIdx.x * 4 + (threadIdx.x >> 6);
  int lane = threadIdx.x & 63;
  f32x4 v = ((const f32x4*)(x + (size_t)row * DMODEL))[lane];
  float ss = v[0]*v[0] + v[1]*v[1] + v[2]*v[2] + v[3]*v[3];
  #pragma unroll
  for (int off = 1; off < 64; off <<= 1) ss += __shfl_xor(ss, off);
  float rms = rsqrtf(ss * (1.0f / DMODEL) + 1e-8f);
  f32x4 wv = ((const f32x4*)w)[lane];
  if constexpr (sizeof(OUT) == 4) {
    f32x4 o;
    o[0] = v[0]*rms*wv[0]; o[1] = v[1]*rms*wv[1]; o[2] = v[2]*rms*wv[2]; o[3] = v[3]*rms*wv[3];
    ((f32x4*)((float*)out + (size_t)row * DMODEL))[lane] = o;
  } else {
    bf16x4 o;
    o[0] = (__bf16)(v[0]*rms*wv[0]); o[1] = (__bf16)(v[1]*rms*wv[1]);
    o[2] = (__bf16)(v[2]*rms*wv[2]); o[3] = (__bf16)(v[3]*rms*wv[3]);
    ((bf16x4*)((__bf16*)out + (size_t)row * DMODEL))[lane] = o;
  }
}

// ---------------- gelu (tanh approx, matches jax.nn.gelu default) ----------------
__device__ __forceinline__ float gelu_f(float v) {
  return 0.5f * v * (1.0f + tanhf(0.7978845608028654f * (v + 0.044715f * v * v * v)));
}

// ---------------- bf16 MFMA GEMM: C(MxN) = A(MxK) @ Bt(NxK)^T ----------------
template<bool RES, bool GELU, bool OUTB>
__launch_bounds__(256)
__global__ void gemm_bt(const __bf16* __restrict__ A, const __bf16* __restrict__ Bt,
                        __bf16* __restrict__ outb, float* __restrict__ res,
                        int K, int N) {
  int tid = threadIdx.x;
  int lane = tid & 63;
  int w = tid >> 6;
  int wr = w >> 1, wc = w & 1;
  int lr = lane & 15;
  int lkb = (lane >> 4) << 3;
  size_t bm = (size_t)blockIdx.x * 128, bn = (size_t)blockIdx.y * 128;
  const __bf16* Ap = A + (bm + wr * 64 + lr) * (size_t)K + lkb;
  const __bf16* Bp = Bt + (bn + wc * 64 + lr) * (size_t)K + lkb;
  f32x4 acc[4][4] = {};
  #pragma unroll 2
  for (int kk = 0; kk < K; kk += 32) {
    bf16x8 av[4], bv[4];
    #pragma unroll
    for (int i = 0; i < 4; ++i) av[i] = *(const bf16x8*)(Ap + (size_t)i * 16 * K + kk);
    #pragma unroll
    for (int i = 0; i < 4; ++i) bv[i] = *(const bf16x8*)(Bp + (size_t)i * 16 * K + kk);
    #pragma unroll
    for (int mi = 0; mi < 4; ++mi)
      #pragma unroll
      for (int ni = 0; ni < 4; ++ni)
        acc[mi][ni] = __builtin_amdgcn_mfma_f32_16x16x32_bf16(av[mi], bv[ni], acc[mi][ni], 0, 0, 0);
  }
  size_t row0 = bm + wr * 64 + ((lane >> 4) << 2);
  size_t col0 = bn + wc * 64 + lr;
  #pragma unroll
  for (int mi = 0; mi < 4; ++mi)
    #pragma unroll
    for (int ni = 0; ni < 4; ++ni)
      #pragma unroll
      for (int j = 0; j < 4; ++j) {
        size_t row = row0 + mi * 16 + j, col = col0 + ni * 16;
        float val = acc[mi][ni][j];
        if constexpr (GELU) val = gelu_f(val);
        if constexpr (RES)  res[row * N + col] += val;
        if constexpr (OUTB) outb[row * N + col] = (__bf16)val;
      }
}

// ---------------- block-sparse attention, MFMA version ----------------
// grid = B*H*nB = 2048 blocks, 256 threads (4 waves). qkv: (16384, 768) bf16.
// Per block: 64 queries x 448 selected keys x dh=32; wave w owns queries [16w,16w+16).
// Swapped QK^T: S^T = K @ Q^T  (per tile t: lane(q=lane&15, g=lane>>4) holds
// S^T[16t+4g+j][q], j=0..3 -> all 448 scores of query q live in 4 lanes).
// PV as O^T = V^T @ P^T: A-frag from LDS Vt (transposed, swizzled), B-frag from
// wave-private LDS P-ring (128 keys, double-buffered, swizzled).
// LDS: K[448][32] bf16 @0 (28672) | Vt[32][448] bf16 swz @28672 (28672)
//      | Pring[4 waves][16][128] bf16 swz @57344 (16384)  => 73728 B, 2 blocks/CU.
#define ATTN_LDS 73728

__launch_bounds__(256)
__global__ void attn_k(const __bf16* __restrict__ qkv, const int* __restrict__ rand_idx,
                       __bf16* __restrict__ o) {
  extern __shared__ char sm[];
  char* smK  = sm;
  char* smVt = sm + 28672;
  int tid = threadIdx.x;
  int lane = tid & 63;
  int w = tid >> 6;
  char* smP = sm + 57344 + w * 4096;
  int q16 = lane & 15, g = lane >> 4;

  int bid = blockIdx.x;
  int b = bid >> 8;
  int hh = (bid >> 5) & 7;
  int n = bid & 31;
  int r5 = rand_idx[n * 2], r6 = rand_idx[n * 2 + 1];
  int nm1 = n > 0 ? n - 1 : 0;
  int np1 = n < 31 ? n + 1 : 31;
  size_t base = (size_t)b * 2048;

  // ---- stage K: [448][32] bf16 linear (reg roundtrip, coalesced) ----
  #pragma unroll
  for (int it = 0; it < 7; ++it) {
    int chunk = it * 256 + tid;             // 16B chunk id, 0..1791
    int r = chunk >> 2, c16 = chunk & 3;    // selected-key row, 16B-col
    int m = r >> 6, si = r & 63;
    int kb = m == 0 ? 0 : m == 1 ? 1 : m == 2 ? nm1 : m == 3 ? n : m == 4 ? np1 : m == 5 ? r5 : r6;
    u32x4 d = *(const u32x4*)(qkv + (base + kb * 64 + si) * 768 + 256 + hh * 32 + c16 * 8);
    *(u32x4*)(smK + chunk * 16) = d;
  }

  // ---- stage V transposed: Vt[d][k], byte ^= ((d>>1)&7)<<4 ----
  #pragma unroll 2
  for (int it = 0; it < 14; ++it) {
    int idx = it * 256 + tid;               // 0..3583
    int dp = idx & 15;                      // d-pair id (d = 2dp, 2dp+1)
    int kp = idx >> 4;                      // k-pair id (k = 2kp, 2kp+1), 0..223
    int k0 = kp * 2;
    int m = k0 >> 6, si = k0 & 63;
    int kb = m == 0 ? 0 : m == 1 ? 1 : m == 2 ? nm1 : m == 3 ? n : m == 4 ? np1 : m == 5 ? r5 : r6;
    const unsigned* vs = (const unsigned*)(qkv + (base + kb * 64 + si) * 768 + 512 + hh * 32) + dp;
    unsigned D0 = vs[0];
    unsigned D1 = vs[384];                  // next key row (+768 elems)
    unsigned w0 = (D0 & 0xffffu) | (D1 << 16);          // Vt[2dp][k0], Vt[2dp][k0+1]
    unsigned w1 = (D0 >> 16) | (D1 & 0xffff0000u);      // Vt[2dp+1][k0], Vt[2dp+1][k0+1]
    unsigned swz = (unsigned)((dp & 7) << 4);
    *(unsigned*)(smVt + (((2 * dp) * 896 + k0 * 2) ^ swz)) = w0;
    *(unsigned*)(smVt + (((2 * dp + 1) * 896 + k0 * 2) ^ swz)) = w1;
  }

  // ---- Q B-frag: lane(q16,g) holds Q[qrow][8g..8g+7] ----
  bf16x8 qf = *(const bf16x8*)(qkv + (base + n * 64 + w * 16 + q16) * 768 + hh * 32 + g * 8);

  __syncthreads();

  // ---- QK^T: 28 tiles of S^T = K @ Q^T (one mfma each, Kdim=dh=32) ----
  f32x4 st[28];
  #pragma unroll
  for (int t = 0; t < 28; ++t) {
    bf16x8 kf = *(const bf16x8*)(smK + (16 * t + q16) * 64 + g * 16);
    st[t] = __builtin_amdgcn_mfma_f32_16x16x32_bf16(kf, qf, (f32x4){0.f, 0.f, 0.f, 0.f}, 0, 0, 0);
  }

  // ---- row max (4 independent chains, then cross-g reduce) ----
  float m0 = st[0][0], m1 = st[0][1], m2 = st[0][2], m3 = st[0][3];
  #pragma unroll
  for (int t = 1; t < 28; ++t) {
    m0 = fmaxf(m0, st[t][0]); m1 = fmaxf(m1, st[t][1]);
    m2 = fmaxf(m2, st[t][2]); m3 = fmaxf(m3, st[t][3]);
  }
  float mx = fmaxf(fmaxf(m0, m1), fmaxf(m2, m3));
  mx = fmaxf(mx, __shfl_xor(mx, 16));
  mx = fmaxf(mx, __shfl_xor(mx, 32));
  const float SC = 0.17677669529663687f * 1.4426950408889634f;  // scale * log2(e)
  float mc = mx * SC;

  // ---- chunked: exp -> pack -> ring write -> PV mfma (7 chunks of 64 keys) ----
  f32x4 oacc[2] = {};
  float ssum = 0.f;
  #pragma unroll
  for (int c = 0; c < 7; ++c) {
    // pack 4 tiles of P into the ring
    #pragma unroll
    for (int tl = 0; tl < 4; ++tl) {
      int t = 4 * c + tl;
      float e0 = __builtin_amdgcn_exp2f(fmaf(st[t][0], SC, -mc));
      float e1 = __builtin_amdgcn_exp2f(fmaf(st[t][1], SC, -mc));
      float e2 = __builtin_amdgcn_exp2f(fmaf(st[t][2], SC, -mc));
      float e3 = __builtin_amdgcn_exp2f(fmaf(st[t][3], SC, -mc));
      ssum += (e0 + e1) + (e2 + e3);
      u32x2 pk;
      pk[0] = (unsigned)bfbits(e0) | ((unsigned)bfbits(e1) << 16);
      pk[1] = (unsigned)bfbits(e2) | ((unsigned)bfbits(e3) << 16);
      // ring byte: q16*256 + 2*((16t+4g) mod 128), swz ^((q16&7)<<4)
      *(u32x2*)(smP + ((q16 * 256 + 32 * (t & 7) + 8 * g) ^ ((q16 & 7) << 4))) = pk;
    }
    // PV: k-steps 2c, 2c+1
    #pragma unroll
    for (int ksl = 0; ksl < 2; ++ksl) {
      int ks = 2 * c + ksl;
      bf16x8 pf = *(const bf16x8*)(smP + ((q16 * 256 + (ks & 3) * 64 + 16 * g) ^ ((q16 & 7) << 4)));
      #pragma unroll
      for (int dt = 0; dt < 2; ++dt) {
        int d = 16 * dt + q16;
        bf16x8 vf = *(const bf16x8*)(smVt + ((d * 896 + 64 * ks + 16 * g) ^ (((d >> 1) & 7) << 4)));
        oacc[dt] = __builtin_amdgcn_mfma_f32_16x16x32_bf16(vf, pf, oacc[dt], 0, 0, 0);
      }
    }
  }

  // ---- normalize + store: lane(q16,g) holds O^T[16dt+4g+j][q16] ----
  ssum += __shfl_xor(ssum, 16);
  ssum += __shfl_xor(ssum, 32);
  float inv = 1.0f / ssum;
  size_t orow = (base + n * 64 + w * 16 + q16) * 256 + hh * 32;
  #pragma unroll
  for (int dt = 0; dt < 2; ++dt) {
    u32x2 pk;
    pk[0] = (unsigned)bfbits(oacc[dt][0] * inv) | ((unsigned)bfbits(oacc[dt][1] * inv) << 16);
    pk[1] = (unsigned)bfbits(oacc[dt][2] * inv) | ((unsigned)bfbits(oacc[dt][3] * inv) << 16);
    *(u32x2*)(o + orow + 16 * dt + 4 * g) = pk;
  }
}

// ---------------- launch ----------------
extern "C" void kernel_launch(void* const* d_in, const int* in_sizes, int n_in,
                              void* d_out, int out_size, void* d_ws, size_t ws_size,
                              hipStream_t stream) {
  const int*   ids      = (const int*)d_in[0];
  const int*   rand_idx = (const int*)d_in[1];
  const float* emb      = (const float*)d_in[2];
  const float* ln1      = (const float*)d_in[3];
  const float* wq       = (const float*)d_in[4];
  const float* wk       = (const float*)d_in[5];
  const float* wv       = (const float*)d_in[6];
  const float* wo       = (const float*)d_in[7];
  const float* ln2      = (const float*)d_in[8];
  const float* w1       = (const float*)d_in[9];
  const float* w2       = (const float*)d_in[10];
  const float* fln      = (const float*)d_in[11];
  float* out = (float*)d_out;

  char* ws = (char*)d_ws;
  float*  x    = (float*)ws;                       // 16,777,216 B
  __bf16* h    = (__bf16*)(ws + 16777216);         //  8,388,608 B
  __bf16* qkv  = (__bf16*)(ws + 25165824);         // 25,165,824 B
  __bf16* obuf = (__bf16*)(ws + 50331648);         //  8,388,608 B
  __bf16* g    = qkv;                              // reuses qkv+obuf, both dead by FFN
  __bf16* wbase = (__bf16*)(ws + 58720256);        //  3,145,728 B

  for (int l = 0; l < 2; ++l) {
    __bf16* qkvT = wbase + (size_t)l * 786432;
    __bf16* woT  = qkvT + 196608;
    __bf16* w1T  = woT + 65536;
    __bf16* w2T  = w1T + 262144;
    transpose_cvt<<<256,  256, 0, stream>>>(wq + (size_t)l * 65536, qkvT,          256, 256);
    transpose_cvt<<<256,  256, 0, stream>>>(wk + (size_t)l * 65536, qkvT + 65536,  256, 256);
    transpose_cvt<<<256,  256, 0, stream>>>(wv + (size_t)l * 65536, qkvT + 131072, 256, 256);
    transpose_cvt<<<256,  256, 0, stream>>>(wo + (size_t)l * 65536, woT,           256, 256);
    transpose_cvt<<<1024, 256, 0, stream>>>(w1 + (size_t)l * 262144, w1T,          256, 1024);
    transpose_cvt<<<1024, 256, 0, stream>>>(w2 + (size_t)l * 262144, w2T,          1024, 256);
  }

  embed_k<<<4096, 256, 0, stream>>>(ids, emb, x);

  for (int l = 0; l < 2; ++l) {
    __bf16* qkvT = wbase + (size_t)l * 786432;
    __bf16* woT  = qkvT + 196608;
    __bf16* w1T  = woT + 65536;
    __bf16* w2T  = w1T + 262144;

    rmsnorm_k<__bf16><<<4096, 256, 0, stream>>>(x, ln1 + (size_t)l * 256, h);
    gemm_bt<false, false, true><<<dim3(128, 6), 256, 0, stream>>>(h, qkvT, qkv, nullptr, 256, 768);
    attn_k<<<2048, 256, ATTN_LDS, stream>>>(qkv, rand_idx, obuf);
    gemm_bt<true, false, false><<<dim3(128, 2), 256, 0, stream>>>(obuf, woT, nullptr, x, 256, 256);
    rmsnorm_k<__bf16><<<4096, 256, 0, stream>>>(x, ln2 + (size_t)l * 256, h);
    gemm_bt<false, true, true><<<dim3(128, 8), 256, 0, stream>>>(h, w1T, g, nullptr, 256, 1024);
    gemm_bt<true, false, false><<<dim3(128, 2), 256, 0, stream>>>(g, w2T, nullptr, x, 1024, 256);
  }

  rmsnorm_k<float><<<4096, 256, 0, stream>>>(x, fln, out);
}

// Round 4
// 499.249 us; speedup vs baseline: 2.4678x; 1.2226x over previous
//
#include <hip/hip_runtime.h>
#include <cstdint>
#include <cstddef>

typedef __bf16 bf16x8 __attribute__((ext_vector_type(8)));
typedef __bf16 bf16x4 __attribute__((ext_vector_type(4)));
typedef float  f32x4  __attribute__((ext_vector_type(4)));
typedef unsigned u32x2 __attribute__((ext_vector_type(2)));
typedef unsigned u32x4 __attribute__((ext_vector_type(4)));

#define DMODEL 256

__device__ __forceinline__ float bflo(unsigned u) { return __builtin_bit_cast(float, u << 16); }
__device__ __forceinline__ float bfhi(unsigned u) { return __builtin_bit_cast(float, u & 0xffff0000u); }
__device__ __forceinline__ unsigned short bfbits(float f) {
  return __builtin_bit_cast(unsigned short, (__bf16)f);
}

// ---------------- all weight transposes in ONE launch ----------------
// wbase layout per layer: [qkvT 196608][woT 65536][w1T 262144][w2T 262144]
__global__ void transpose_all(const float* __restrict__ wq, const float* __restrict__ wk,
                              const float* __restrict__ wv, const float* __restrict__ wo,
                              const float* __restrict__ w1, const float* __restrict__ w2,
                              __bf16* __restrict__ wbase) {
  int idx = blockIdx.x * 256 + threadIdx.x;      // [0, 1572864)
  int l = idx >= 786432;
  int r = idx - l * 786432;
  __bf16* wb = wbase + (size_t)l * 786432;
  const float* s; __bf16* d; int R, C, e;
  if (r < 65536)       { s = wq + l * 65536;  d = wb;          R = 256;  C = 256;  e = r; }
  else if (r < 131072) { s = wk + l * 65536;  d = wb + 65536;  R = 256;  C = 256;  e = r - 65536; }
  else if (r < 196608) { s = wv + l * 65536;  d = wb + 131072; R = 256;  C = 256;  e = r - 131072; }
  else if (r < 262144) { s = wo + l * 65536;  d = wb + 196608; R = 256;  C = 256;  e = r - 196608; }
  else if (r < 524288) { s = w1 + l * 262144; d = wb + 262144; R = 256;  C = 1024; e = r - 262144; }
  else                 { s = w2 + l * 262144; d = wb + 524288; R = 1024; C = 256;  e = r - 524288; }
  int row = e / C, col = e - row * C;
  d[col * R + row] = (__bf16)s[e];
}

// ---------------- embedding gather ----------------
__global__ void embed_k(const int* __restrict__ ids, const float* __restrict__ emb, float* __restrict__ x) {
  int row = blockIdx.x * 4 + (threadIdx.x >> 6);
  int lane = threadIdx.x & 63;
  int id = ids[row];
  ((f32x4*)(x + (size_t)row * DMODEL))[lane] = ((const f32x4*)(emb + (size_t)id * DMODEL))[lane];
}

// ---------------- rmsnorm (one wave per row of 256) ----------------
template<typename OUT>
__global__ void rmsnorm_k(const float* __restrict__ x, const float* __restrict__ w, OUT* __restrict__ out) {
  int row = blockIdx.x * 4 + (threadIdx.x >> 6);
  int lane = threadIdx.x & 63;
  f32x4 v = ((const f32x4*)(x + (size_t)row * DMODEL))[lane];
  float ss = v[0]*v[0] + v[1]*v[1] + v[2]*v[2] + v[3]*v[3];
  #pragma unroll
  for (int off = 1; off < 64; off <<= 1) ss += __shfl_xor(ss, off);
  float rms = rsqrtf(ss * (1.0f / DMODEL) + 1e-8f);
  f32x4 wv = ((const f32x4*)w)[lane];
  if constexpr (sizeof(OUT) == 4) {
    f32x4 o;
    o[0] = v[0]*rms*wv[0]; o[1] = v[1]*rms*wv[1]; o[2] = v[2]*rms*wv[2]; o[3] = v[3]*rms*wv[3];
    ((f32x4*)((float*)out + (size_t)row * DMODEL))[lane] = o;
  } else {
    bf16x4 o;
    o[0] = (__bf16)(v[0]*rms*wv[0]); o[1] = (__bf16)(v[1]*rms*wv[1]);
    o[2] = (__bf16)(v[2]*rms*wv[2]); o[3] = (__bf16)(v[3]*rms*wv[3]);
    ((bf16x4*)((__bf16*)out + (size_t)row * DMODEL))[lane] = o;
  }
}

// ---------------- gelu (tanh approx, matches jax.nn.gelu default) ----------------
__device__ __forceinline__ float gelu_f(float v) {
  return 0.5f * v * (1.0f + tanhf(0.7978845608028654f * (v + 0.044715f * v * v * v)));
}

// ---------------- bf16 MFMA GEMM: C(MxN) = A(MxK) @ Bt(NxK)^T ----------------
template<bool RES, bool GELU, bool OUTB>
__launch_bounds__(256)
__global__ void gemm_bt(const __bf16* __restrict__ A, const __bf16* __restrict__ Bt,
                        __bf16* __restrict__ outb, float* __restrict__ res,
                        int K, int N) {
  int tid = threadIdx.x;
  int lane = tid & 63;
  int w = tid >> 6;
  int wr = w >> 1, wc = w & 1;
  int lr = lane & 15;
  int lkb = (lane >> 4) << 3;
  size_t bm = (size_t)blockIdx.x * 128, bn = (size_t)blockIdx.y * 128;
  const __bf16* Ap = A + (bm + wr * 64 + lr) * (size_t)K + lkb;
  const __bf16* Bp = Bt + (bn + wc * 64 + lr) * (size_t)K + lkb;
  f32x4 acc[4][4] = {};
  #pragma unroll 2
  for (int kk = 0; kk < K; kk += 32) {
    bf16x8 av[4], bv[4];
    #pragma unroll
    for (int i = 0; i < 4; ++i) av[i] = *(const bf16x8*)(Ap + (size_t)i * 16 * K + kk);
    #pragma unroll
    for (int i = 0; i < 4; ++i) bv[i] = *(const bf16x8*)(Bp + (size_t)i * 16 * K + kk);
    #pragma unroll
    for (int mi = 0; mi < 4; ++mi)
      #pragma unroll
      for (int ni = 0; ni < 4; ++ni)
        acc[mi][ni] = __builtin_amdgcn_mfma_f32_16x16x32_bf16(av[mi], bv[ni], acc[mi][ni], 0, 0, 0);
  }
  size_t row0 = bm + wr * 64 + ((lane >> 4) << 2);
  size_t col0 = bn + wc * 64 + lr;
  #pragma unroll
  for (int mi = 0; mi < 4; ++mi)
    #pragma unroll
    for (int ni = 0; ni < 4; ++ni)
      #pragma unroll
      for (int j = 0; j < 4; ++j) {
        size_t row = row0 + mi * 16 + j, col = col0 + ni * 16;
        float val = acc[mi][ni][j];
        if constexpr (GELU) val = gelu_f(val);
        if constexpr (RES)  res[row * N + col] += val;
        if constexpr (OUTB) outb[row * N + col] = (__bf16)val;
      }
}

// ---------------- block-sparse attention, MFMA + register-P version ----------------
// grid = B*H*nB = 2048 blocks, 256 threads (4 waves). qkv: (16384, 768) bf16.
// One 28672B LDS buffer time-shared: K[448][32] (XOR-swizzled) then Vt[32][448]
// (transposed, XOR-swizzled). P^T B-frags built in-register via ds_bpermute from
// the S^T C-layout (no LDS ring). 3 syncthreads. 3 blocks/CU target.
#define ATTN_LDS 28672

__launch_bounds__(256, 3)
__global__ void attn_k(const __bf16* __restrict__ qkv, const int* __restrict__ rand_idx,
                       __bf16* __restrict__ o) {
  extern __shared__ char smKV[];
  int tid = threadIdx.x;
  int lane = tid & 63;
  int w = tid >> 6;
  int q16 = lane & 15, g = lane >> 4;

  int bid = blockIdx.x;
  int b = bid >> 8;
  int hh = (bid >> 5) & 7;
  int n = bid & 31;
  int r5 = rand_idx[n * 2], r6 = rand_idx[n * 2 + 1];
  int nm1 = n > 0 ? n - 1 : 0;
  int np1 = n < 31 ? n + 1 : 31;
  size_t base = (size_t)b * 2048;

  // ---- stage K: rows [448][32] bf16, byte ^= (row&7)<<4 ----
  #pragma unroll
  for (int it = 0; it < 7; ++it) {
    int chunk = it * 256 + tid;             // 16B chunk id, 0..1791
    int r = chunk >> 2, c16 = chunk & 3;    // key row, 16B col
    int m = r >> 6, si = r & 63;
    int kb = m == 0 ? 0 : m == 1 ? 1 : m == 2 ? nm1 : m == 3 ? n : m == 4 ? np1 : m == 5 ? r5 : r6;
    u32x4 d = *(const u32x4*)(qkv + (base + kb * 64 + si) * 768 + 256 + hh * 32 + c16 * 8);
    *(u32x4*)(smKV + ((chunk * 16) ^ ((r & 7) << 4))) = d;
  }

  // ---- Q B-frag ----
  bf16x8 qf = *(const bf16x8*)(qkv + (base + n * 64 + w * 16 + q16) * 768 + hh * 32 + g * 8);

  __syncthreads();

  // ---- QK^T: S^T = K @ Q^T, 28 tiles ----
  f32x4 st[28];
  __builtin_amdgcn_s_setprio(1);
  #pragma unroll
  for (int t = 0; t < 28; ++t) {
    int row = 16 * t + q16;
    bf16x8 kf = *(const bf16x8*)(smKV + ((row * 64 + g * 16) ^ ((q16 & 7) << 4)));
    st[t] = __builtin_amdgcn_mfma_f32_16x16x32_bf16(kf, qf, (f32x4){0.f, 0.f, 0.f, 0.f}, 0, 0, 0);
  }
  __builtin_amdgcn_s_setprio(0);

  // ---- row max ----
  float m0 = st[0][0], m1 = st[0][1], m2 = st[0][2], m3 = st[0][3];
  #pragma unroll
  for (int t = 1; t < 28; ++t) {
    m0 = fmaxf(m0, st[t][0]); m1 = fmaxf(m1, st[t][1]);
    m2 = fmaxf(m2, st[t][2]); m3 = fmaxf(m3, st[t][3]);
  }
  float mx = fmaxf(fmaxf(m0, m1), fmaxf(m2, m3));
  mx = fmaxf(mx, __shfl_xor(mx, 16));
  mx = fmaxf(mx, __shfl_xor(mx, 32));
  const float SC = 0.17677669529663687f * 1.4426950408889634f;  // scale * log2(e)
  float mc = mx * SC;

  // ---- exp + pack to bf16 pairs (frees st into pk) ----
  unsigned pk0[28], pk1[28];
  float ssum = 0.f;
  #pragma unroll
  for (int t = 0; t < 28; ++t) {
    float e0 = __builtin_amdgcn_exp2f(fmaf(st[t][0], SC, -mc));
    float e1 = __builtin_amdgcn_exp2f(fmaf(st[t][1], SC, -mc));
    float e2 = __builtin_amdgcn_exp2f(fmaf(st[t][2], SC, -mc));
    float e3 = __builtin_amdgcn_exp2f(fmaf(st[t][3], SC, -mc));
    ssum += (e0 + e1) + (e2 + e3);
    pk0[t] = (unsigned)bfbits(e0) | ((unsigned)bfbits(e1) << 16);
    pk1[t] = (unsigned)bfbits(e2) | ((unsigned)bfbits(e3) << 16);
  }
  ssum += __shfl_xor(ssum, 16);
  ssum += __shfl_xor(ssum, 32);
  float inv = 1.0f / ssum;

  // ---- V gather: 8 keys x 2 dims per item, into regs ----
  unsigned vreg[4][8];
  #pragma unroll
  for (int it = 0; it < 4; ++it) {
    int item = it * 256 + tid;              // [0, 896)
    if (item < 896) {
      int dp = item & 15, ko = item >> 4;   // dim-pair, key-octet
      int s0 = ko * 8;
      int m = s0 >> 6, si = s0 & 63;
      int kb = m == 0 ? 0 : m == 1 ? 1 : m == 2 ? nm1 : m == 3 ? n : m == 4 ? np1 : m == 5 ? r5 : r6;
      const unsigned* vs = (const unsigned*)(qkv + (base + kb * 64 + si) * 768 + 512 + hh * 32) + dp;
      #pragma unroll
      for (int i = 0; i < 8; ++i) vreg[it][i] = vs[(size_t)i * 384];
    }
  }

  __syncthreads();   // all QK reads of smKV done -> safe to overwrite with Vt

  // ---- write Vt[d][k] bf16, byte ^= ((d>>1)&7)<<4, b128 ----
  #pragma unroll
  for (int it = 0; it < 4; ++it) {
    int item = it * 256 + tid;
    if (item < 896) {
      int dp = item & 15, ko = item >> 4;
      u32x4 lo4, hi4;
      #pragma unroll
      for (int wd = 0; wd < 4; ++wd) {
        unsigned a = vreg[it][2 * wd], bb = vreg[it][2 * wd + 1];
        lo4[wd] = (a & 0xffffu) | (bb << 16);
        hi4[wd] = (a >> 16) | (bb & 0xffff0000u);
      }
      unsigned swz = (unsigned)((dp & 7) << 4);
      int byte0 = (2 * dp) * 896 + ko * 16;
      *(u32x4*)(smKV + (byte0 ^ swz)) = lo4;
      *(u32x4*)(smKV + ((byte0 + 896) ^ swz)) = hi4;
    }
  }

  __syncthreads();

  // ---- PV: O^T = V^T @ P^T, P^T B-frags via bpermute from pk ----
  int src0 = q16 + 32 * (g & 1);
  int src1 = src0 + 16;
  bool hi = (g >= 2);
  f32x4 oacc[2] = {};
  __builtin_amdgcn_s_setprio(1);
  #pragma unroll
  for (int ks = 0; ks < 14; ++ks) {
    unsigned a0 = __shfl(pk0[2 * ks], src0), b0 = __shfl(pk0[2 * ks + 1], src0);
    unsigned a1 = __shfl(pk1[2 * ks], src0), b1 = __shfl(pk1[2 * ks + 1], src0);
    unsigned a2 = __shfl(pk0[2 * ks], src1), b2 = __shfl(pk0[2 * ks + 1], src1);
    unsigned a3 = __shfl(pk1[2 * ks], src1), b3 = __shfl(pk1[2 * ks + 1], src1);
    u32x4 pw;
    pw[0] = hi ? b0 : a0; pw[1] = hi ? b1 : a1;
    pw[2] = hi ? b2 : a2; pw[3] = hi ? b3 : a3;
    bf16x8 pf = __builtin_bit_cast(bf16x8, pw);
    #pragma unroll
    for (int dt = 0; dt < 2; ++dt) {
      int d = 16 * dt + q16;
      bf16x8 vf = *(const bf16x8*)(smKV + ((d * 896 + 64 * ks + 16 * g) ^ (((d >> 1) & 7) << 4)));
      oacc[dt] = __builtin_amdgcn_mfma_f32_16x16x32_bf16(vf, pf, oacc[dt], 0, 0, 0);
    }
  }
  __builtin_amdgcn_s_setprio(0);

  // ---- normalize + store: lane(q16,g) holds O^T[16dt+4g+j][q16] ----
  size_t orow = (base + n * 64 + w * 16 + q16) * 256 + hh * 32;
  #pragma unroll
  for (int dt = 0; dt < 2; ++dt) {
    u32x2 pk;
    pk[0] = (unsigned)bfbits(oacc[dt][0] * inv) | ((unsigned)bfbits(oacc[dt][1] * inv) << 16);
    pk[1] = (unsigned)bfbits(oacc[dt][2] * inv) | ((unsigned)bfbits(oacc[dt][3] * inv) << 16);
    *(u32x2*)(o + orow + 16 * dt + 4 * g) = pk;
  }
}

// ---------------- launch ----------------
extern "C" void kernel_launch(void* const* d_in, const int* in_sizes, int n_in,
                              void* d_out, int out_size, void* d_ws, size_t ws_size,
                              hipStream_t stream) {
  const int*   ids      = (const int*)d_in[0];
  const int*   rand_idx = (const int*)d_in[1];
  const float* emb      = (const float*)d_in[2];
  const float* ln1      = (const float*)d_in[3];
  const float* wq       = (const float*)d_in[4];
  const float* wk       = (const float*)d_in[5];
  const float* wv       = (const float*)d_in[6];
  const float* wo       = (const float*)d_in[7];
  const float* ln2      = (const float*)d_in[8];
  const float* w1       = (const float*)d_in[9];
  const float* w2       = (const float*)d_in[10];
  const float* fln      = (const float*)d_in[11];
  float* out = (float*)d_out;

  char* ws = (char*)d_ws;
  float*  x    = (float*)ws;                       // 16,777,216 B
  __bf16* h    = (__bf16*)(ws + 16777216);         //  8,388,608 B
  __bf16* qkv  = (__bf16*)(ws + 25165824);         // 25,165,824 B
  __bf16* obuf = (__bf16*)(ws + 50331648);         //  8,388,608 B
  __bf16* g    = qkv;                              // reuses qkv+obuf, both dead by FFN
  __bf16* wbase = (__bf16*)(ws + 58720256);        //  3,145,728 B

  transpose_all<<<6144, 256, 0, stream>>>(wq, wk, wv, wo, w1, w2, wbase);
  embed_k<<<4096, 256, 0, stream>>>(ids, emb, x);

  for (int l = 0; l < 2; ++l) {
    __bf16* qkvT = wbase + (size_t)l * 786432;
    __bf16* woT  = qkvT + 196608;
    __bf16* w1T  = woT + 65536;
    __bf16* w2T  = w1T + 262144;

    rmsnorm_k<__bf16><<<4096, 256, 0, stream>>>(x, ln1 + (size_t)l * 256, h);
    gemm_bt<false, false, true><<<dim3(128, 6), 256, 0, stream>>>(h, qkvT, qkv, nullptr, 256, 768);
    attn_k<<<2048, 256, ATTN_LDS, stream>>>(qkv, rand_idx, obuf);
    gemm_bt<true, false, false><<<dim3(128, 2), 256, 0, stream>>>(obuf, woT, nullptr, x, 256, 256);
    rmsnorm_k<__bf16><<<4096, 256, 0, stream>>>(x, ln2 + (size_t)l * 256, h);
    gemm_bt<false, true, true><<<dim3(128, 8), 256, 0, stream>>>(h, w1T, g, nullptr, 256, 1024);
    gemm_bt<true, false, false><<<dim3(128, 2), 256, 0, stream>>>(g, w2T, nullptr, x, 1024, 256);
  }

  rmsnorm_k<float><<<4096, 256, 0, stream>>>(x, fln, out);
}

// Round 5
// 408.524 us; speedup vs baseline: 3.0159x; 1.2221x over previous
//
#include <hip/hip_runtime.h>
#include <cstdint>
#include <cstddef>

typedef __bf16 bf16x8 __attribute__((ext_vector_type(8)));
typedef __bf16 bf16x4 __attribute__((ext_vector_type(4)));
typedef float  f32x4  __attribute__((ext_vector_type(4)));
typedef unsigned u32x2 __attribute__((ext_vector_type(2)));
typedef unsigned u32x4 __attribute__((ext_vector_type(4)));

#define DMODEL 256

__device__ __forceinline__ float bflo(unsigned u) { return __builtin_bit_cast(float, u << 16); }
__device__ __forceinline__ float bfhi(unsigned u) { return __builtin_bit_cast(float, u & 0xffff0000u); }
__device__ __forceinline__ unsigned short bfbits(float f) {
  return __builtin_bit_cast(unsigned short, (__bf16)f);
}

// async global->LDS, 16B per lane; LDS dest = base + lane*16 (wave-uniform base)
#define GLOAD_LDS16(gp, lp) __builtin_amdgcn_global_load_lds(                 \
    (const __attribute__((address_space(1))) unsigned*)(gp),                  \
    (__attribute__((address_space(3))) unsigned*)(lp), 16, 0, 0)

// ---------------- all weight transposes in ONE launch ----------------
__global__ void transpose_all(const float* __restrict__ wq, const float* __restrict__ wk,
                              const float* __restrict__ wv, const float* __restrict__ wo,
                              const float* __restrict__ w1, const float* __restrict__ w2,
                              __bf16* __restrict__ wbase) {
  int idx = blockIdx.x * 256 + threadIdx.x;      // [0, 1572864)
  int l = idx >= 786432;
  int r = idx - l * 786432;
  __bf16* wb = wbase + (size_t)l * 786432;
  const float* s; __bf16* d; int R, C, e;
  if (r < 65536)       { s = wq + l * 65536;  d = wb;          R = 256;  C = 256;  e = r; }
  else if (r < 131072) { s = wk + l * 65536;  d = wb + 65536;  R = 256;  C = 256;  e = r - 65536; }
  else if (r < 196608) { s = wv + l * 65536;  d = wb + 131072; R = 256;  C = 256;  e = r - 131072; }
  else if (r < 262144) { s = wo + l * 65536;  d = wb + 196608; R = 256;  C = 256;  e = r - 196608; }
  else if (r < 524288) { s = w1 + l * 262144; d = wb + 262144; R = 256;  C = 1024; e = r - 262144; }
  else                 { s = w2 + l * 262144; d = wb + 524288; R = 1024; C = 256;  e = r - 524288; }
  int row = e / C, col = e - row * C;
  d[col * R + row] = (__bf16)s[e];
}

// ---------------- embedding gather ----------------
__global__ void embed_k(const int* __restrict__ ids, const float* __restrict__ emb, float* __restrict__ x) {
  int row = blockIdx.x * 4 + (threadIdx.x >> 6);
  int lane = threadIdx.x & 63;
  int id = ids[row];
  ((f32x4*)(x + (size_t)row * DMODEL))[lane] = ((const f32x4*)(emb + (size_t)id * DMODEL))[lane];
}

// ---------------- rmsnorm (one wave per row of 256) ----------------
template<typename OUT>
__global__ void rmsnorm_k(const float* __restrict__ x, const float* __restrict__ w, OUT* __restrict__ out) {
  int row = blockIdx.x * 4 + (threadIdx.x >> 6);
  int lane = threadIdx.x & 63;
  f32x4 v = ((const f32x4*)(x + (size_t)row * DMODEL))[lane];
  float ss = v[0]*v[0] + v[1]*v[1] + v[2]*v[2] + v[3]*v[3];
  #pragma unroll
  for (int off = 1; off < 64; off <<= 1) ss += __shfl_xor(ss, off);
  float rms = rsqrtf(ss * (1.0f / DMODEL) + 1e-8f);
  f32x4 wv = ((const f32x4*)w)[lane];
  if constexpr (sizeof(OUT) == 4) {
    f32x4 o;
    o[0] = v[0]*rms*wv[0]; o[1] = v[1]*rms*wv[1]; o[2] = v[2]*rms*wv[2]; o[3] = v[3]*rms*wv[3];
    ((f32x4*)((float*)out + (size_t)row * DMODEL))[lane] = o;
  } else {
    bf16x4 o;
    o[0] = (__bf16)(v[0]*rms*wv[0]); o[1] = (__bf16)(v[1]*rms*wv[1]);
    o[2] = (__bf16)(v[2]*rms*wv[2]); o[3] = (__bf16)(v[3]*rms*wv[3]);
    ((bf16x4*)((__bf16*)out + (size_t)row * DMODEL))[lane] = o;
  }
}

// ---------------- gelu (tanh approx, matches jax.nn.gelu default) ----------------
__device__ __forceinline__ float gelu_f(float v) {
  return 0.5f * v * (1.0f + tanhf(0.7978845608028654f * (v + 0.044715f * v * v * v)));
}

// ---------------- bf16 MFMA GEMM, LDS double-buffered (m97 structure) ----------------
// C(MxN) = A(MxK) @ Bt(NxK)^T. 128x128 tile, BK=32, 4 waves (2x2 of 64x64).
// Stage: global_load_lds width=16, A-tile [128][32] + B-tile [128][32] linear,
// double-buffered (2 x 16 KiB). 8 ds_read_b128 + 16 MFMA per wave per k-step.
template<bool RES, bool GELU, bool OUTB>
__launch_bounds__(256)
__global__ void gemm_bt(const __bf16* __restrict__ A, const __bf16* __restrict__ Bt,
                        __bf16* __restrict__ outb, float* __restrict__ res,
                        int K, int N) {
  __shared__ char sm[32768];
  int tid = threadIdx.x;
  int lane = tid & 63;
  int w = tid >> 6;
  int wr = w >> 1, wc = w & 1;
  int lr = lane & 15;
  int hk = lane >> 4;
  size_t bm = (size_t)blockIdx.x * 128, bn = (size_t)blockIdx.y * 128;
  const __bf16* Ab = A + bm * (size_t)K;
  const __bf16* Bb = Bt + bn * (size_t)K;

  // staging chunk ids for this lane (16B units within the 8 KiB half-tile)
  int u0 = w * 128 + lane;
  int r0 = u0 >> 2, c0 = u0 & 3;
  int u1 = u0 + 64;
  int r1 = u1 >> 2, c1 = u1 & 3;
  size_t ga0 = (size_t)r0 * K + c0 * 8;   // element offsets
  size_t ga1 = (size_t)r1 * K + c1 * 8;
  int lb0 = (w * 2) * 1024;               // LDS byte bases (per-instruction)
  int lb1 = (w * 2 + 1) * 1024;

  int nt = K >> 5;
  // prologue: stage tile 0 into buf 0
  GLOAD_LDS16(Ab + ga0, sm + lb0);
  GLOAD_LDS16(Bb + ga0, sm + 8192 + lb0);
  GLOAD_LDS16(Ab + ga1, sm + lb1);
  GLOAD_LDS16(Bb + ga1, sm + 8192 + lb1);
  __syncthreads();

  f32x4 acc[4][4] = {};
  for (int t = 0; t < nt; ++t) {
    char* cur = sm + (t & 1) * 16384;
    if (t + 1 < nt) {
      char* nxt = sm + ((t + 1) & 1) * 16384;
      int kk = (t + 1) * 32;
      GLOAD_LDS16(Ab + ga0 + kk, nxt + lb0);
      GLOAD_LDS16(Bb + ga0 + kk, nxt + 8192 + lb0);
      GLOAD_LDS16(Ab + ga1 + kk, nxt + lb1);
      GLOAD_LDS16(Bb + ga1 + kk, nxt + 8192 + lb1);
    }
    bf16x8 av[4], bv[4];
    #pragma unroll
    for (int i = 0; i < 4; ++i)
      av[i] = *(const bf16x8*)(cur + (wr * 64 + i * 16 + lr) * 64 + hk * 16);
    #pragma unroll
    for (int i = 0; i < 4; ++i)
      bv[i] = *(const bf16x8*)(cur + 8192 + (wc * 64 + i * 16 + lr) * 64 + hk * 16);
    #pragma unroll
    for (int mi = 0; mi < 4; ++mi)
      #pragma unroll
      for (int ni = 0; ni < 4; ++ni)
        acc[mi][ni] = __builtin_amdgcn_mfma_f32_16x16x32_bf16(av[mi], bv[ni], acc[mi][ni], 0, 0, 0);
    __syncthreads();
  }

  size_t row0 = bm + wr * 64 + (hk << 2);
  size_t col0 = bn + wc * 64 + lr;
  #pragma unroll
  for (int mi = 0; mi < 4; ++mi)
    #pragma unroll
    for (int ni = 0; ni < 4; ++ni)
      #pragma unroll
      for (int j = 0; j < 4; ++j) {
        size_t row = row0 + mi * 16 + j, col = col0 + ni * 16;
        float val = acc[mi][ni][j];
        if constexpr (GELU) val = gelu_f(val);
        if constexpr (RES)  res[row * N + col] += val;
        if constexpr (OUTB) outb[row * N + col] = (__bf16)val;
      }
}

// ---------------- block-sparse attention, MFMA + register-P version ----------------
#define ATTN_LDS 28672

__launch_bounds__(256, 3)
__global__ void attn_k(const __bf16* __restrict__ qkv, const int* __restrict__ rand_idx,
                       __bf16* __restrict__ o) {
  extern __shared__ char smKV[];
  int tid = threadIdx.x;
  int lane = tid & 63;
  int w = tid >> 6;
  int q16 = lane & 15, g = lane >> 4;

  int bid = blockIdx.x;
  int b = bid >> 8;
  int hh = (bid >> 5) & 7;
  int n = bid & 31;
  int r5 = rand_idx[n * 2], r6 = rand_idx[n * 2 + 1];
  int nm1 = n > 0 ? n - 1 : 0;
  int np1 = n < 31 ? n + 1 : 31;
  size_t base = (size_t)b * 2048;

  // ---- stage K: rows [448][32] bf16, byte ^= (row&7)<<4 ----
  #pragma unroll
  for (int it = 0; it < 7; ++it) {
    int chunk = it * 256 + tid;             // 16B chunk id, 0..1791
    int r = chunk >> 2, c16 = chunk & 3;    // key row, 16B col
    int m = r >> 6, si = r & 63;
    int kb = m == 0 ? 0 : m == 1 ? 1 : m == 2 ? nm1 : m == 3 ? n : m == 4 ? np1 : m == 5 ? r5 : r6;
    u32x4 d = *(const u32x4*)(qkv + (base + kb * 64 + si) * 768 + 256 + hh * 32 + c16 * 8);
    *(u32x4*)(smKV + ((chunk * 16) ^ ((r & 7) << 4))) = d;
  }

  // ---- Q B-frag ----
  bf16x8 qf = *(const bf16x8*)(qkv + (base + n * 64 + w * 16 + q16) * 768 + hh * 32 + g * 8);

  __syncthreads();

  // ---- QK^T: S^T = K @ Q^T, 28 tiles ----
  f32x4 st[28];
  __builtin_amdgcn_s_setprio(1);
  #pragma unroll
  for (int t = 0; t < 28; ++t) {
    int row = 16 * t + q16;
    bf16x8 kf = *(const bf16x8*)(smKV + ((row * 64 + g * 16) ^ ((q16 & 7) << 4)));
    st[t] = __builtin_amdgcn_mfma_f32_16x16x32_bf16(kf, qf, (f32x4){0.f, 0.f, 0.f, 0.f}, 0, 0, 0);
  }
  __builtin_amdgcn_s_setprio(0);

  // ---- row max ----
  float m0 = st[0][0], m1 = st[0][1], m2 = st[0][2], m3 = st[0][3];
  #pragma unroll
  for (int t = 1; t < 28; ++t) {
    m0 = fmaxf(m0, st[t][0]); m1 = fmaxf(m1, st[t][1]);
    m2 = fmaxf(m2, st[t][2]); m3 = fmaxf(m3, st[t][3]);
  }
  float mx = fmaxf(fmaxf(m0, m1), fmaxf(m2, m3));
  mx = fmaxf(mx, __shfl_xor(mx, 16));
  mx = fmaxf(mx, __shfl_xor(mx, 32));
  const float SC = 0.17677669529663687f * 1.4426950408889634f;  // scale * log2(e)
  float mc = mx * SC;

  // ---- exp + pack to bf16 pairs ----
  unsigned pk0[28], pk1[28];
  float ssum = 0.f;
  #pragma unroll
  for (int t = 0; t < 28; ++t) {
    float e0 = __builtin_amdgcn_exp2f(fmaf(st[t][0], SC, -mc));
    float e1 = __builtin_amdgcn_exp2f(fmaf(st[t][1], SC, -mc));
    float e2 = __builtin_amdgcn_exp2f(fmaf(st[t][2], SC, -mc));
    float e3 = __builtin_amdgcn_exp2f(fmaf(st[t][3], SC, -mc));
    ssum += (e0 + e1) + (e2 + e3);
    pk0[t] = (unsigned)bfbits(e0) | ((unsigned)bfbits(e1) << 16);
    pk1[t] = (unsigned)bfbits(e2) | ((unsigned)bfbits(e3) << 16);
  }
  ssum += __shfl_xor(ssum, 16);
  ssum += __shfl_xor(ssum, 32);
  float inv = 1.0f / ssum;

  // ---- V gather: 8 keys x 2 dims per item, into regs ----
  unsigned vreg[4][8];
  #pragma unroll
  for (int it = 0; it < 4; ++it) {
    int item = it * 256 + tid;              // [0, 896)
    if (item < 896) {
      int dp = item & 15, ko = item >> 4;   // dim-pair, key-octet
      int s0 = ko * 8;
      int m = s0 >> 6, si = s0 & 63;
      int kb = m == 0 ? 0 : m == 1 ? 1 : m == 2 ? nm1 : m == 3 ? n : m == 4 ? np1 : m == 5 ? r5 : r6;
      const unsigned* vs = (const unsigned*)(qkv + (base + kb * 64 + si) * 768 + 512 + hh * 32) + dp;
      #pragma unroll
      for (int i = 0; i < 8; ++i) vreg[it][i] = vs[(size_t)i * 384];
    }
  }

  __syncthreads();   // all QK reads of smKV done -> safe to overwrite with Vt

  // ---- write Vt[d][k] bf16, byte ^= ((d>>1)&7)<<4, b128 ----
  #pragma unroll
  for (int it = 0; it < 4; ++it) {
    int item = it * 256 + tid;
    if (item < 896) {
      int dp = item & 15, ko = item >> 4;
      u32x4 lo4, hi4;
      #pragma unroll
      for (int wd = 0; wd < 4; ++wd) {
        unsigned a = vreg[it][2 * wd], bb = vreg[it][2 * wd + 1];
        lo4[wd] = (a & 0xffffu) | (bb << 16);
        hi4[wd] = (a >> 16) | (bb & 0xffff0000u);
      }
      unsigned swz = (unsigned)((dp & 7) << 4);
      int byte0 = (2 * dp) * 896 + ko * 16;
      *(u32x4*)(smKV + (byte0 ^ swz)) = lo4;
      *(u32x4*)(smKV + ((byte0 + 896) ^ swz)) = hi4;
    }
  }

  __syncthreads();

  // ---- PV: O^T = V^T @ P^T, P^T B-frags via shfl from pk ----
  int src0 = q16 + 32 * (g & 1);
  int src1 = src0 + 16;
  bool hi = (g >= 2);
  f32x4 oacc[2] = {};
  __builtin_amdgcn_s_setprio(1);
  #pragma unroll
  for (int ks = 0; ks < 14; ++ks) {
    unsigned a0 = __shfl(pk0[2 * ks], src0), b0 = __shfl(pk0[2 * ks + 1], src0);
    unsigned a1 = __shfl(pk1[2 * ks], src0), b1 = __shfl(pk1[2 * ks + 1], src0);
    unsigned a2 = __shfl(pk0[2 * ks], src1), b2 = __shfl(pk0[2 * ks + 1], src1);
    unsigned a3 = __shfl(pk1[2 * ks], src1), b3 = __shfl(pk1[2 * ks + 1], src1);
    u32x4 pw;
    pw[0] = hi ? b0 : a0; pw[1] = hi ? b1 : a1;
    pw[2] = hi ? b2 : a2; pw[3] = hi ? b3 : a3;
    bf16x8 pf = __builtin_bit_cast(bf16x8, pw);
    #pragma unroll
    for (int dt = 0; dt < 2; ++dt) {
      int d = 16 * dt + q16;
      bf16x8 vf = *(const bf16x8*)(smKV + ((d * 896 + 64 * ks + 16 * g) ^ (((d >> 1) & 7) << 4)));
      oacc[dt] = __builtin_amdgcn_mfma_f32_16x16x32_bf16(vf, pf, oacc[dt], 0, 0, 0);
    }
  }
  __builtin_amdgcn_s_setprio(0);

  // ---- normalize + store ----
  size_t orow = (base + n * 64 + w * 16 + q16) * 256 + hh * 32;
  #pragma unroll
  for (int dt = 0; dt < 2; ++dt) {
    u32x2 pk;
    pk[0] = (unsigned)bfbits(oacc[dt][0] * inv) | ((unsigned)bfbits(oacc[dt][1] * inv) << 16);
    pk[1] = (unsigned)bfbits(oacc[dt][2] * inv) | ((unsigned)bfbits(oacc[dt][3] * inv) << 16);
    *(u32x2*)(o + orow + 16 * dt + 4 * g) = pk;
  }
}

// ---------------- launch ----------------
extern "C" void kernel_launch(void* const* d_in, const int* in_sizes, int n_in,
                              void* d_out, int out_size, void* d_ws, size_t ws_size,
                              hipStream_t stream) {
  const int*   ids      = (const int*)d_in[0];
  const int*   rand_idx = (const int*)d_in[1];
  const float* emb      = (const float*)d_in[2];
  const float* ln1      = (const float*)d_in[3];
  const float* wq       = (const float*)d_in[4];
  const float* wk       = (const float*)d_in[5];
  const float* wv       = (const float*)d_in[6];
  const float* wo       = (const float*)d_in[7];
  const float* ln2      = (const float*)d_in[8];
  const float* w1       = (const float*)d_in[9];
  const float* w2       = (const float*)d_in[10];
  const float* fln      = (const float*)d_in[11];
  float* out = (float*)d_out;

  char* ws = (char*)d_ws;
  float*  x    = (float*)ws;                       // 16,777,216 B
  __bf16* h    = (__bf16*)(ws + 16777216);         //  8,388,608 B
  __bf16* qkv  = (__bf16*)(ws + 25165824);         // 25,165,824 B
  __bf16* obuf = (__bf16*)(ws + 50331648);         //  8,388,608 B
  __bf16* g    = qkv;                              // reuses qkv+obuf, both dead by FFN
  __bf16* wbase = (__bf16*)(ws + 58720256);        //  3,145,728 B

  transpose_all<<<6144, 256, 0, stream>>>(wq, wk, wv, wo, w1, w2, wbase);
  embed_k<<<4096, 256, 0, stream>>>(ids, emb, x);

  for (int l = 0; l < 2; ++l) {
    __bf16* qkvT = wbase + (size_t)l * 786432;
    __bf16* woT  = qkvT + 196608;
    __bf16* w1T  = woT + 65536;
    __bf16* w2T  = w1T + 262144;

    rmsnorm_k<__bf16><<<4096, 256, 0, stream>>>(x, ln1 + (size_t)l * 256, h);
    gemm_bt<false, false, true><<<dim3(128, 6), 256, 0, stream>>>(h, qkvT, qkv, nullptr, 256, 768);
    attn_k<<<2048, 256, ATTN_LDS, stream>>>(qkv, rand_idx, obuf);
    gemm_bt<true, false, false><<<dim3(128, 2), 256, 0, stream>>>(obuf, woT, nullptr, x, 256, 256);
    rmsnorm_k<__bf16><<<4096, 256, 0, stream>>>(x, ln2 + (size_t)l * 256, h);
    gemm_bt<false, true, true><<<dim3(128, 8), 256, 0, stream>>>(h, w1T, g, nullptr, 256, 1024);
    gemm_bt<true, false, false><<<dim3(128, 2), 256, 0, stream>>>(g, w2T, nullptr, x, 1024, 256);
  }

  rmsnorm_k<float><<<4096, 256, 0, stream>>>(x, fln, out);
}

// Round 6
// 400.246 us; speedup vs baseline: 3.0783x; 1.0207x over previous
//
#include <hip/hip_runtime.h>
#include <cstdint>
#include <cstddef>

typedef __bf16 bf16x8 __attribute__((ext_vector_type(8)));
typedef __bf16 bf16x4 __attribute__((ext_vector_type(4)));
typedef float  f32x4  __attribute__((ext_vector_type(4)));
typedef unsigned u32x2 __attribute__((ext_vector_type(2)));
typedef unsigned u32x4 __attribute__((ext_vector_type(4)));

#define DMODEL 256

__device__ __forceinline__ float bflo(unsigned u) { return __builtin_bit_cast(float, u << 16); }
__device__ __forceinline__ float bfhi(unsigned u) { return __builtin_bit_cast(float, u & 0xffff0000u); }
__device__ __forceinline__ unsigned short bfbits(float f) {
  return __builtin_bit_cast(unsigned short, (__bf16)f);
}

// async global->LDS, 16B per lane; LDS dest = base + lane*16 (wave-uniform base)
#define GLOAD_LDS16(gp, lp) __builtin_amdgcn_global_load_lds(                 \
    (const __attribute__((address_space(1))) unsigned*)(gp),                  \
    (__attribute__((address_space(3))) unsigned*)(lp), 16, 0, 0)

// ---------------- all weight transposes in ONE launch ----------------
__global__ void transpose_all(const float* __restrict__ wq, const float* __restrict__ wk,
                              const float* __restrict__ wv, const float* __restrict__ wo,
                              const float* __restrict__ w1, const float* __restrict__ w2,
                              __bf16* __restrict__ wbase) {
  int idx = blockIdx.x * 256 + threadIdx.x;      // [0, 1572864)
  int l = idx >= 786432;
  int r = idx - l * 786432;
  __bf16* wb = wbase + (size_t)l * 786432;
  const float* s; __bf16* d; int R, C, e;
  if (r < 65536)       { s = wq + l * 65536;  d = wb;          R = 256;  C = 256;  e = r; }
  else if (r < 131072) { s = wk + l * 65536;  d = wb + 65536;  R = 256;  C = 256;  e = r - 65536; }
  else if (r < 196608) { s = wv + l * 65536;  d = wb + 131072; R = 256;  C = 256;  e = r - 131072; }
  else if (r < 262144) { s = wo + l * 65536;  d = wb + 196608; R = 256;  C = 256;  e = r - 196608; }
  else if (r < 524288) { s = w1 + l * 262144; d = wb + 262144; R = 256;  C = 1024; e = r - 262144; }
  else                 { s = w2 + l * 262144; d = wb + 524288; R = 1024; C = 256;  e = r - 524288; }
  int row = e / C, col = e - row * C;
  d[col * R + row] = (__bf16)s[e];
}

// ---------------- embedding gather ----------------
__global__ void embed_k(const int* __restrict__ ids, const float* __restrict__ emb, float* __restrict__ x) {
  int row = blockIdx.x * 4 + (threadIdx.x >> 6);
  int lane = threadIdx.x & 63;
  int id = ids[row];
  ((f32x4*)(x + (size_t)row * DMODEL))[lane] = ((const f32x4*)(emb + (size_t)id * DMODEL))[lane];
}

// ---------------- rmsnorm (one wave per row of 256) ----------------
template<typename OUT>
__global__ void rmsnorm_k(const float* __restrict__ x, const float* __restrict__ w, OUT* __restrict__ out) {
  int row = blockIdx.x * 4 + (threadIdx.x >> 6);
  int lane = threadIdx.x & 63;
  f32x4 v = ((const f32x4*)(x + (size_t)row * DMODEL))[lane];
  float ss = v[0]*v[0] + v[1]*v[1] + v[2]*v[2] + v[3]*v[3];
  #pragma unroll
  for (int off = 1; off < 64; off <<= 1) ss += __shfl_xor(ss, off);
  float rms = rsqrtf(ss * (1.0f / DMODEL) + 1e-8f);
  f32x4 wv = ((const f32x4*)w)[lane];
  if constexpr (sizeof(OUT) == 4) {
    f32x4 o;
    o[0] = v[0]*rms*wv[0]; o[1] = v[1]*rms*wv[1]; o[2] = v[2]*rms*wv[2]; o[3] = v[3]*rms*wv[3];
    ((f32x4*)((float*)out + (size_t)row * DMODEL))[lane] = o;
  } else {
    bf16x4 o;
    o[0] = (__bf16)(v[0]*rms*wv[0]); o[1] = (__bf16)(v[1]*rms*wv[1]);
    o[2] = (__bf16)(v[2]*rms*wv[2]); o[3] = (__bf16)(v[3]*rms*wv[3]);
    ((bf16x4*)((__bf16*)out + (size_t)row * DMODEL))[lane] = o;
  }
}

// ---------------- gelu (tanh approx, matches jax.nn.gelu default) ----------------
__device__ __forceinline__ float gelu_f(float v) {
  return 0.5f * v * (1.0f + tanhf(0.7978845608028654f * (v + 0.044715f * v * v * v)));
}

// ---------------- bf16 MFMA GEMM, LDS double-buffered (m97 structure) ----------------
template<bool RES, bool GELU, bool OUTB>
__launch_bounds__(256)
__global__ void gemm_bt(const __bf16* __restrict__ A, const __bf16* __restrict__ Bt,
                        __bf16* __restrict__ outb, float* __restrict__ res,
                        int K, int N) {
  __shared__ char sm[32768];
  int tid = threadIdx.x;
  int lane = tid & 63;
  int w = tid >> 6;
  int wr = w >> 1, wc = w & 1;
  int lr = lane & 15;
  int hk = lane >> 4;
  size_t bm = (size_t)blockIdx.x * 128, bn = (size_t)blockIdx.y * 128;
  const __bf16* Ab = A + bm * (size_t)K;
  const __bf16* Bb = Bt + bn * (size_t)K;

  int u0 = w * 128 + lane;
  int r0 = u0 >> 2, c0 = u0 & 3;
  int u1 = u0 + 64;
  int r1 = u1 >> 2, c1 = u1 & 3;
  size_t ga0 = (size_t)r0 * K + c0 * 8;
  size_t ga1 = (size_t)r1 * K + c1 * 8;
  int lb0 = (w * 2) * 1024;
  int lb1 = (w * 2 + 1) * 1024;

  int nt = K >> 5;
  GLOAD_LDS16(Ab + ga0, sm + lb0);
  GLOAD_LDS16(Bb + ga0, sm + 8192 + lb0);
  GLOAD_LDS16(Ab + ga1, sm + lb1);
  GLOAD_LDS16(Bb + ga1, sm + 8192 + lb1);
  __syncthreads();

  f32x4 acc[4][4] = {};
  for (int t = 0; t < nt; ++t) {
    char* cur = sm + (t & 1) * 16384;
    if (t + 1 < nt) {
      char* nxt = sm + ((t + 1) & 1) * 16384;
      int kk = (t + 1) * 32;
      GLOAD_LDS16(Ab + ga0 + kk, nxt + lb0);
      GLOAD_LDS16(Bb + ga0 + kk, nxt + 8192 + lb0);
      GLOAD_LDS16(Ab + ga1 + kk, nxt + lb1);
      GLOAD_LDS16(Bb + ga1 + kk, nxt + 8192 + lb1);
    }
    bf16x8 av[4], bv[4];
    #pragma unroll
    for (int i = 0; i < 4; ++i)
      av[i] = *(const bf16x8*)(cur + (wr * 64 + i * 16 + lr) * 64 + hk * 16);
    #pragma unroll
    for (int i = 0; i < 4; ++i)
      bv[i] = *(const bf16x8*)(cur + 8192 + (wc * 64 + i * 16 + lr) * 64 + hk * 16);
    #pragma unroll
    for (int mi = 0; mi < 4; ++mi)
      #pragma unroll
      for (int ni = 0; ni < 4; ++ni)
        acc[mi][ni] = __builtin_amdgcn_mfma_f32_16x16x32_bf16(av[mi], bv[ni], acc[mi][ni], 0, 0, 0);
    __syncthreads();
  }

  size_t row0 = bm + wr * 64 + (hk << 2);
  size_t col0 = bn + wc * 64 + lr;
  #pragma unroll
  for (int mi = 0; mi < 4; ++mi)
    #pragma unroll
    for (int ni = 0; ni < 4; ++ni)
      #pragma unroll
      for (int j = 0; j < 4; ++j) {
        size_t row = row0 + mi * 16 + j, col = col0 + ni * 16;
        float val = acc[mi][ni][j];
        if constexpr (GELU) val = gelu_f(val);
        if constexpr (RES)  res[row * N + col] += val;
        if constexpr (OUTB) outb[row * N + col] = (__bf16)val;
      }
}

// ---------------- block-sparse attention: flash-chunked, no spill ----------------
// grid = 2048, 256 threads (4 waves). XCD-chunked bid swizzle: XCD x <- batch b=x
// (3.1 MB qkv slice per XCD L2). LDS: K[448][32] swz @0 | Vt[32][448] swz @28672.
// One __syncthreads total; per-wave flash loop over 7 chunks of 64 keys with
// online softmax (defer-max THR=8 in exp2 space). Live regs/chunk: st[4]+pk[8].
#define ATTN_LDS 57344

__launch_bounds__(256)
__global__ void attn_k(const __bf16* __restrict__ qkv, const int* __restrict__ rand_idx,
                       __bf16* __restrict__ o) {
  extern __shared__ char sm[];
  char* smVt = sm + 28672;
  int tid = threadIdx.x;
  int lane = tid & 63;
  int w = tid >> 6;
  int q16 = lane & 15, g = lane >> 4;

  int bid0 = blockIdx.x;
  int bid = (bid0 & 7) * 256 + (bid0 >> 3);   // XCD-chunked: b = XCD id
  int b = bid >> 8;
  int hh = (bid >> 5) & 7;
  int n = bid & 31;
  int r5 = rand_idx[n * 2], r6 = rand_idx[n * 2 + 1];
  int nm1 = n > 0 ? n - 1 : 0;
  int np1 = n < 31 ? n + 1 : 31;
  size_t base = (size_t)b * 2048;

  // ---- stage K: rows [448][32] bf16, byte ^= (row&7)<<4 ----
  #pragma unroll
  for (int it = 0; it < 7; ++it) {
    int chunk = it * 256 + tid;             // 16B chunk id, 0..1791
    int r = chunk >> 2, c16 = chunk & 3;
    int m = r >> 6, si = r & 63;
    int kb = m == 0 ? 0 : m == 1 ? 1 : m == 2 ? nm1 : m == 3 ? n : m == 4 ? np1 : m == 5 ? r5 : r6;
    u32x4 d = *(const u32x4*)(qkv + (base + kb * 64 + si) * 768 + 256 + hh * 32 + c16 * 8);
    *(u32x4*)(sm + ((chunk * 16) ^ ((r & 7) << 4))) = d;
  }

  // ---- stage Vt[d][k] bf16 (transpose in regs), byte ^= ((d>>1)&7)<<4 ----
  #pragma unroll
  for (int it = 0; it < 4; ++it) {
    int item = it * 256 + tid;              // [0, 896)
    if (item < 896) {
      int dp = item & 15, ko = item >> 4;   // dim-pair, key-octet
      int s0 = ko * 8;
      int m = s0 >> 6, si = s0 & 63;
      int kb = m == 0 ? 0 : m == 1 ? 1 : m == 2 ? nm1 : m == 3 ? n : m == 4 ? np1 : m == 5 ? r5 : r6;
      const unsigned* vs = (const unsigned*)(qkv + (base + kb * 64 + si) * 768 + 512 + hh * 32) + dp;
      unsigned vr[8];
      #pragma unroll
      for (int i = 0; i < 8; ++i) vr[i] = vs[(size_t)i * 384];
      u32x4 lo4, hi4;
      #pragma unroll
      for (int wd = 0; wd < 4; ++wd) {
        unsigned a = vr[2 * wd], bb = vr[2 * wd + 1];
        lo4[wd] = (a & 0xffffu) | (bb << 16);
        hi4[wd] = (a >> 16) | (bb & 0xffff0000u);
      }
      unsigned swz = (unsigned)((dp & 7) << 4);
      int byte0 = (2 * dp) * 896 + ko * 16;
      *(u32x4*)(smVt + (byte0 ^ swz)) = lo4;
      *(u32x4*)(smVt + ((byte0 + 896) ^ swz)) = hi4;
    }
  }

  // ---- Q B-frag: lane(q16,g) holds Q[qrow][8g..8g+7] ----
  bf16x8 qf = *(const bf16x8*)(qkv + (base + n * 64 + w * 16 + q16) * 768 + hh * 32 + g * 8);

  __syncthreads();

  // ---- flash loop: 7 chunks x 64 keys, online softmax ----
  const float SC  = 0.17677669529663687f * 1.4426950408889634f;  // scale * log2(e)
  const float THR = 8.0f / SC;                                   // defer-max threshold
  int src0 = q16 + 32 * (g & 1);
  int src1 = src0 + 16;
  bool hi = (g >= 2);
  float m_run = -1e30f, mc = 0.f, ssum = 0.f;
  f32x4 oacc[2] = {};
  bool first = true;

  #pragma unroll
  for (int c = 0; c < 7; ++c) {
    // QK^T: 4 tiles (S^T = K @ Q^T)
    f32x4 st[4];
    #pragma unroll
    for (int tl = 0; tl < 4; ++tl) {
      int row = 16 * (4 * c + tl) + q16;
      bf16x8 kf = *(const bf16x8*)(sm + ((row * 64 + g * 16) ^ ((q16 & 7) << 4)));
      st[tl] = __builtin_amdgcn_mfma_f32_16x16x32_bf16(kf, qf, (f32x4){0.f, 0.f, 0.f, 0.f}, 0, 0, 0);
    }
    // local max (this chunk), reduced across the 4 lanes of each query
    float lm = st[0][0];
    #pragma unroll
    for (int tl = 0; tl < 4; ++tl) {
      lm = fmaxf(lm, fmaxf(fmaxf(st[tl][0], st[tl][1]), fmaxf(st[tl][2], st[tl][3])));
    }
    lm = fmaxf(lm, __shfl_xor(lm, 16));
    lm = fmaxf(lm, __shfl_xor(lm, 32));
    // online-max update, deferred unless growth > THR
    if (first || !__all(lm <= m_run + THR)) {
      float nm = fmaxf(m_run, lm);
      float sf = __builtin_amdgcn_exp2f((m_run - nm) * SC);   // 0 on first chunk
      ssum *= sf;
      #pragma unroll
      for (int dt = 0; dt < 2; ++dt)
        #pragma unroll
        for (int j = 0; j < 4; ++j) oacc[dt][j] *= sf;
      m_run = nm;
      mc = nm * SC;
      first = false;
    }
    // exp + pack
    unsigned pk0[4], pk1[4];
    #pragma unroll
    for (int tl = 0; tl < 4; ++tl) {
      float e0 = __builtin_amdgcn_exp2f(fmaf(st[tl][0], SC, -mc));
      float e1 = __builtin_amdgcn_exp2f(fmaf(st[tl][1], SC, -mc));
      float e2 = __builtin_amdgcn_exp2f(fmaf(st[tl][2], SC, -mc));
      float e3 = __builtin_amdgcn_exp2f(fmaf(st[tl][3], SC, -mc));
      ssum += (e0 + e1) + (e2 + e3);
      pk0[tl] = (unsigned)bfbits(e0) | ((unsigned)bfbits(e1) << 16);
      pk1[tl] = (unsigned)bfbits(e2) | ((unsigned)bfbits(e3) << 16);
    }
    // PV: 2 k-steps of O^T = V^T @ P^T (P frags via shfl)
    #pragma unroll
    for (int ksl = 0; ksl < 2; ++ksl) {
      int ks = 2 * c + ksl;
      int lt0 = 2 * ksl, lt1 = 2 * ksl + 1;
      unsigned a0 = __shfl(pk0[lt0], src0), b0 = __shfl(pk0[lt1], src0);
      unsigned a1 = __shfl(pk1[lt0], src0), b1 = __shfl(pk1[lt1], src0);
      unsigned a2 = __shfl(pk0[lt0], src1), b2 = __shfl(pk0[lt1], src1);
      unsigned a3 = __shfl(pk1[lt0], src1), b3 = __shfl(pk1[lt1], src1);
      u32x4 pw;
      pw[0] = hi ? b0 : a0; pw[1] = hi ? b1 : a1;
      pw[2] = hi ? b2 : a2; pw[3] = hi ? b3 : a3;
      bf16x8 pf = __builtin_bit_cast(bf16x8, pw);
      #pragma unroll
      for (int dt = 0; dt < 2; ++dt) {
        int d = 16 * dt + q16;
        bf16x8 vf = *(const bf16x8*)(smVt + ((d * 896 + 64 * ks + 16 * g) ^ (((d >> 1) & 7) << 4)));
        oacc[dt] = __builtin_amdgcn_mfma_f32_16x16x32_bf16(vf, pf, oacc[dt], 0, 0, 0);
      }
    }
  }

  // ---- normalize + store: lane(q16,g) holds O^T[16dt+4g+j][q16] ----
  ssum += __shfl_xor(ssum, 16);
  ssum += __shfl_xor(ssum, 32);
  float inv = 1.0f / ssum;
  size_t orow = (base + n * 64 + w * 16 + q16) * 256 + hh * 32;
  #pragma unroll
  for (int dt = 0; dt < 2; ++dt) {
    u32x2 pk;
    pk[0] = (unsigned)bfbits(oacc[dt][0] * inv) | ((unsigned)bfbits(oacc[dt][1] * inv) << 16);
    pk[1] = (unsigned)bfbits(oacc[dt][2] * inv) | ((unsigned)bfbits(oacc[dt][3] * inv) << 16);
    *(u32x2*)(o + orow + 16 * dt + 4 * g) = pk;
  }
}

// ---------------- launch ----------------
extern "C" void kernel_launch(void* const* d_in, const int* in_sizes, int n_in,
                              void* d_out, int out_size, void* d_ws, size_t ws_size,
                              hipStream_t stream) {
  const int*   ids      = (const int*)d_in[0];
  const int*   rand_idx = (const int*)d_in[1];
  const float* emb      = (const float*)d_in[2];
  const float* ln1      = (const float*)d_in[3];
  const float* wq       = (const float*)d_in[4];
  const float* wk       = (const float*)d_in[5];
  const float* wv       = (const float*)d_in[6];
  const float* wo       = (const float*)d_in[7];
  const float* ln2      = (const float*)d_in[8];
  const float* w1       = (const float*)d_in[9];
  const float* w2       = (const float*)d_in[10];
  const float* fln      = (const float*)d_in[11];
  float* out = (float*)d_out;

  char* ws = (char*)d_ws;
  float*  x    = (float*)ws;                       // 16,777,216 B
  __bf16* h    = (__bf16*)(ws + 16777216);         //  8,388,608 B
  __bf16* qkv  = (__bf16*)(ws + 25165824);         // 25,165,824 B
  __bf16* obuf = (__bf16*)(ws + 50331648);         //  8,388,608 B
  __bf16* g    = qkv;                              // reuses qkv+obuf, both dead by FFN
  __bf16* wbase = (__bf16*)(ws + 58720256);        //  3,145,728 B

  transpose_all<<<6144, 256, 0, stream>>>(wq, wk, wv, wo, w1, w2, wbase);
  embed_k<<<4096, 256, 0, stream>>>(ids, emb, x);

  for (int l = 0; l < 2; ++l) {
    __bf16* qkvT = wbase + (size_t)l * 786432;
    __bf16* woT  = qkvT + 196608;
    __bf16* w1T  = woT + 65536;
    __bf16* w2T  = w1T + 262144;

    rmsnorm_k<__bf16><<<4096, 256, 0, stream>>>(x, ln1 + (size_t)l * 256, h);
    gemm_bt<false, false, true><<<dim3(128, 6), 256, 0, stream>>>(h, qkvT, qkv, nullptr, 256, 768);
    attn_k<<<2048, 256, ATTN_LDS, stream>>>(qkv, rand_idx, obuf);
    gemm_bt<true, false, false><<<dim3(128, 2), 256, 0, stream>>>(obuf, woT, nullptr, x, 256, 256);
    rmsnorm_k<__bf16><<<4096, 256, 0, stream>>>(x, ln2 + (size_t)l * 256, h);
    gemm_bt<false, true, true><<<dim3(128, 8), 256, 0, stream>>>(h, w1T, g, nullptr, 256, 1024);
    gemm_bt<true, false, false><<<dim3(128, 2), 256, 0, stream>>>(g, w2T, nullptr, x, 1024, 256);
  }

  rmsnorm_k<float><<<4096, 256, 0, stream>>>(x, fln, out);
}

// Round 8
// 335.588 us; speedup vs baseline: 3.6714x; 1.1927x over previous
//
#include <hip/hip_runtime.h>
#include <cstdint>
#include <cstddef>

typedef __bf16 bf16x8 __attribute__((ext_vector_type(8)));
typedef __bf16 bf16x4 __attribute__((ext_vector_type(4)));
typedef float  f32x4  __attribute__((ext_vector_type(4)));
typedef unsigned u32x2 __attribute__((ext_vector_type(2)));
typedef unsigned u32x4 __attribute__((ext_vector_type(4)));

#define DMODEL 256

__device__ __forceinline__ unsigned short bfbits(float f) {
  return __builtin_bit_cast(unsigned short, (__bf16)f);
}

// async global->LDS, 16B per lane; LDS dest = base + lane*16 (wave-uniform base)
#define GLOAD_LDS16(gp, lp) __builtin_amdgcn_global_load_lds(                 \
    (const __attribute__((address_space(1))) unsigned*)(gp),                  \
    (__attribute__((address_space(3))) unsigned*)(lp), 16, 0, 0)

// ---------------- all weight transposes in ONE launch ----------------
__global__ void transpose_all(const float* __restrict__ wq, const float* __restrict__ wk,
                              const float* __restrict__ wv, const float* __restrict__ wo,
                              const float* __restrict__ w1, const float* __restrict__ w2,
                              __bf16* __restrict__ wbase) {
  int idx = blockIdx.x * 256 + threadIdx.x;      // [0, 1572864)
  int l = idx >= 786432;
  int r = idx - l * 786432;
  __bf16* wb = wbase + (size_t)l * 786432;
  const float* s; __bf16* d; int R, C, e;
  if (r < 65536)       { s = wq + l * 65536;  d = wb;          R = 256;  C = 256;  e = r; }
  else if (r < 131072) { s = wk + l * 65536;  d = wb + 65536;  R = 256;  C = 256;  e = r - 65536; }
  else if (r < 196608) { s = wv + l * 65536;  d = wb + 131072; R = 256;  C = 256;  e = r - 131072; }
  else if (r < 262144) { s = wo + l * 65536;  d = wb + 196608; R = 256;  C = 256;  e = r - 196608; }
  else if (r < 524288) { s = w1 + l * 262144; d = wb + 262144; R = 256;  C = 1024; e = r - 262144; }
  else                 { s = w2 + l * 262144; d = wb + 524288; R = 1024; C = 256;  e = r - 524288; }
  int row = e / C, col = e - row * C;
  d[col * R + row] = (__bf16)s[e];
}

// ---------------- embedding gather ----------------
__global__ void embed_k(const int* __restrict__ ids, const float* __restrict__ emb, float* __restrict__ x) {
  int row = blockIdx.x * 4 + (threadIdx.x >> 6);
  int lane = threadIdx.x & 63;
  int id = ids[row];
  ((f32x4*)(x + (size_t)row * DMODEL))[lane] = ((const f32x4*)(emb + (size_t)id * DMODEL))[lane];
}

// ---------------- rmsnorm (one wave per row of 256) ----------------
template<typename OUT>
__global__ void rmsnorm_k(const float* __restrict__ x, const float* __restrict__ w, OUT* __restrict__ out) {
  int row = blockIdx.x * 4 + (threadIdx.x >> 6);
  int lane = threadIdx.x & 63;
  f32x4 v = ((const f32x4*)(x + (size_t)row * DMODEL))[lane];
  float ss = v[0]*v[0] + v[1]*v[1] + v[2]*v[2] + v[3]*v[3];
  #pragma unroll
  for (int off = 1; off < 64; off <<= 1) ss += __shfl_xor(ss, off);
  float rms = rsqrtf(ss * (1.0f / DMODEL) + 1e-8f);
  f32x4 wv = ((const f32x4*)w)[lane];
  if constexpr (sizeof(OUT) == 4) {
    f32x4 o;
    o[0] = v[0]*rms*wv[0]; o[1] = v[1]*rms*wv[1]; o[2] = v[2]*rms*wv[2]; o[3] = v[3]*rms*wv[3];
    ((f32x4*)((float*)out + (size_t)row * DMODEL))[lane] = o;
  } else {
    bf16x4 o;
    o[0] = (__bf16)(v[0]*rms*wv[0]); o[1] = (__bf16)(v[1]*rms*wv[1]);
    o[2] = (__bf16)(v[2]*rms*wv[2]); o[3] = (__bf16)(v[3]*rms*wv[3]);
    ((bf16x4*)((__bf16*)out + (size_t)row * DMODEL))[lane] = o;
  }
}

// ---------------- gelu: 0.5v(1+tanh(u)) == v*sigmoid(2u), u=0.79788456(v+0.044715v^3)
__device__ __forceinline__ float gelu_f(float v) {
  float u = v + 0.044715f * v * v * v;
  float s = __builtin_amdgcn_exp2f(-2.3022080898f * u);   // exp(-2*0.79788456*u)
  return v * __builtin_amdgcn_rcpf(1.0f + s);
}

// ---------------- bf16 MFMA GEMM, LDS double-buffered (m97 structure) ----------------
// C(MxN) = A(MxK) @ Bt(NxK)^T. BM x 128 tile (BM=128 or 64), BK=32, 4 waves (2x2).
// Wave tile (BM/2) x 64. Stage via global_load_lds width=16, double-buffered.
template<int BM, bool RES, bool GELU, bool OUTB>
__launch_bounds__(256)
__global__ void gemm_bt(const __bf16* __restrict__ A, const __bf16* __restrict__ Bt,
                        __bf16* __restrict__ outb, float* __restrict__ res,
                        int K, int N) {
  constexpr int WTM = BM / 2;           // wave tile rows
  constexpr int MT = WTM / 16;          // A frags per wave
  constexpr int ABYTES = BM * 64;       // A tile bytes (32 k x 2B)
  constexpr int TILE = ABYTES + 8192;   // + B tile 128x32x2B
  constexpr int LOADS = BM / 64 + 2;    // 16B chunks per thread per tile
  __shared__ char sm[2 * TILE];
  int tid = threadIdx.x;
  int lane = tid & 63;
  int w = tid >> 6;
  int wr = w >> 1, wc = w & 1;
  int lr = lane & 15;
  int hk = lane >> 4;
  size_t bm = (size_t)blockIdx.x * BM, bn = (size_t)blockIdx.y * 128;
  const __bf16* Ab = A + bm * (size_t)K;
  const __bf16* Bb = Bt + bn * (size_t)K;

  const __bf16* gsrc[LOADS];
  int ldst[LOADS];
  #pragma unroll
  for (int i = 0; i < LOADS; ++i) {
    int chunk = i * 256 + tid;
    if (chunk < BM * 4) {               // A chunk
      int r = chunk >> 2, c16 = chunk & 3;
      gsrc[i] = Ab + (size_t)r * K + c16 * 8;
      ldst[i] = chunk * 16;
    } else {                            // B chunk
      int cb = chunk - BM * 4;
      int r = cb >> 2, c16 = cb & 3;
      gsrc[i] = Bb + (size_t)r * K + c16 * 8;
      ldst[i] = ABYTES + cb * 16;
    }
  }

  int nt = K >> 5;
  #pragma unroll
  for (int i = 0; i < LOADS; ++i) GLOAD_LDS16(gsrc[i], sm + ldst[i]);
  __syncthreads();

  f32x4 acc[MT][4] = {};
  for (int t = 0; t < nt; ++t) {
    char* cur = sm + (t & 1) * TILE;
    if (t + 1 < nt) {
      char* nxt = sm + ((t + 1) & 1) * TILE;
      int kk = (t + 1) * 32;
      #pragma unroll
      for (int i = 0; i < LOADS; ++i) GLOAD_LDS16(gsrc[i] + kk, nxt + ldst[i]);
    }
    bf16x8 av[MT], bv[4];
    #pragma unroll
    for (int i = 0; i < MT; ++i)
      av[i] = *(const bf16x8*)(cur + (wr * WTM + i * 16 + lr) * 64 + hk * 16);
    #pragma unroll
    for (int i = 0; i < 4; ++i)
      bv[i] = *(const bf16x8*)(cur + ABYTES + (wc * 64 + i * 16 + lr) * 64 + hk * 16);
    #pragma unroll
    for (int mi = 0; mi < MT; ++mi)
      #pragma unroll
      for (int ni = 0; ni < 4; ++ni)
        acc[mi][ni] = __builtin_amdgcn_mfma_f32_16x16x32_bf16(av[mi], bv[ni], acc[mi][ni], 0, 0, 0);
    __syncthreads();
  }

  size_t row0 = bm + wr * WTM + (hk << 2);
  size_t col0 = bn + wc * 64 + lr;
  #pragma unroll
  for (int mi = 0; mi < MT; ++mi)
    #pragma unroll
    for (int ni = 0; ni < 4; ++ni)
      #pragma unroll
      for (int j = 0; j < 4; ++j) {
        size_t row = row0 + mi * 16 + j, col = col0 + ni * 16;
        float val = acc[mi][ni][j];
        if constexpr (GELU) val = gelu_f(val);
        if constexpr (RES)  res[row * N + col] += val;
        if constexpr (OUTB) outb[row * N + col] = (__bf16)val;
      }
}

// ---------------- block-sparse attention: flash, per-chunk K/V double-buffer ----------------
// grid = 2048 (XCD-chunked swizzle), 256 threads (4 waves). Per chunk c (= selected
// key-block m): K[64][32] swz + Vt[32][64] swz in 8KB buf, double-buffered (16KB LDS
// -> 8 blocks/CU). T14: issue global loads for c+1, compute c, LDS-write c+1, barrier.
#define ATTN_LDS 16384
#define ABUF 8192

__launch_bounds__(256)
__global__ void attn_k(const __bf16* __restrict__ qkv, const int* __restrict__ rand_idx,
                       __bf16* __restrict__ o) {
  extern __shared__ char sm[];
  int tid = threadIdx.x;
  int lane = tid & 63;
  int w = tid >> 6;
  int q16 = lane & 15, g = lane >> 4;

  int bid0 = blockIdx.x;
  int bid = (bid0 & 7) * 256 + (bid0 >> 3);   // XCD-chunked: b = XCD id
  int b = bid >> 8;
  int hh = (bid >> 5) & 7;
  int n = bid & 31;
  int r5 = rand_idx[n * 2], r6 = rand_idx[n * 2 + 1];
  int nm1 = n > 0 ? n - 1 : 0;
  int np1 = n < 31 ? n + 1 : 31;
  size_t base = (size_t)b * 2048;
  int kbs[7] = {0, 1, nm1, n, np1, r5, r6};

  // per-thread staging roles
  int ksi = tid >> 2, kc16 = tid & 3;         // K: row, 16B col
  int vdp = tid & 15, vko = tid >> 4;         // V: dim-pair, key-quad (4 keys)

  // ---- Q B-frag: lane(q16,g) holds Q[qrow][8g..8g+7] ----
  bf16x8 qf = *(const bf16x8*)(qkv + (base + n * 64 + w * 16 + q16) * 768 + hh * 32 + g * 8);

  const float SC  = 0.17677669529663687f * 1.4426950408889634f;  // scale * log2(e)
  const float THR = 8.0f / SC;
  int src0 = q16 + 32 * (g & 1);
  int src1 = src0 + 16;
  bool hi = (g >= 2);
  float m_run = -1e30f, mc = 0.f, ssum = 0.f;
  f32x4 oacc[2] = {};
  bool first = true;

  // ---- prologue: stage chunk 0 into buf 0 ----
  u32x4 kreg;
  unsigned vr0, vr1, vr2, vr3;
  {
    int kb = kbs[0];
    kreg = *(const u32x4*)(qkv + (base + kb * 64 + ksi) * 768 + 256 + hh * 32 + kc16 * 8);
    const unsigned* vs = (const unsigned*)(qkv + (base + kb * 64 + vko * 4) * 768 + 512 + hh * 32) + vdp;
    vr0 = vs[0]; vr1 = vs[384]; vr2 = vs[768]; vr3 = vs[1152];
  }
  {
    char* bp = sm;
    *(u32x4*)(bp + ((tid * 16) ^ (((tid >> 2) & 7) << 4))) = kreg;
    u32x2 lo2, hi2;
    lo2[0] = (vr0 & 0xffffu) | (vr1 << 16);  lo2[1] = (vr2 & 0xffffu) | (vr3 << 16);
    hi2[0] = (vr0 >> 16) | (vr1 & 0xffff0000u); hi2[1] = (vr2 >> 16) | (vr3 & 0xffff0000u);
    unsigned swz = (unsigned)((vdp & 7) << 4);
    int byte0 = vdp * 256 + vko * 8;          // row 2*vdp (128B stride), keys 4*vko
    *(u32x2*)(bp + 4096 + (byte0 ^ swz)) = lo2;
    *(u32x2*)(bp + 4096 + ((byte0 + 128) ^ swz)) = hi2;
  }
  __syncthreads();

  // ---- main loop over 7 chunks of 64 keys ----
  #pragma unroll
  for (int c = 0; c < 7; ++c) {
    char* cur = sm + (c & 1) * ABUF;
    // T14 issue-early: global loads for chunk c+1
    if (c < 6) {
      int kb = kbs[c + 1];
      kreg = *(const u32x4*)(qkv + (base + kb * 64 + ksi) * 768 + 256 + hh * 32 + kc16 * 8);
      const unsigned* vs = (const unsigned*)(qkv + (base + kb * 64 + vko * 4) * 768 + 512 + hh * 32) + vdp;
      vr0 = vs[0]; vr1 = vs[384]; vr2 = vs[768]; vr3 = vs[1152];
    }

    // QK^T: 4 tiles (S^T = K @ Q^T), chunk-local rows
    f32x4 st[4];
    #pragma unroll
    for (int tl = 0; tl < 4; ++tl) {
      int row = 16 * tl + q16;
      bf16x8 kf = *(const bf16x8*)(cur + ((row * 64 + g * 16) ^ ((q16 & 7) << 4)));
      st[tl] = __builtin_amdgcn_mfma_f32_16x16x32_bf16(kf, qf, (f32x4){0.f, 0.f, 0.f, 0.f}, 0, 0, 0);
    }
    // chunk max
    float lm = st[0][0];
    #pragma unroll
    for (int tl = 0; tl < 4; ++tl)
      lm = fmaxf(lm, fmaxf(fmaxf(st[tl][0], st[tl][1]), fmaxf(st[tl][2], st[tl][3])));
    lm = fmaxf(lm, __shfl_xor(lm, 16));
    lm = fmaxf(lm, __shfl_xor(lm, 32));
    if (first || !__all(lm <= m_run + THR)) {
      float nm = fmaxf(m_run, lm);
      float sf = __builtin_amdgcn_exp2f((m_run - nm) * SC);   // 0 on first chunk
      ssum *= sf;
      #pragma unroll
      for (int dt = 0; dt < 2; ++dt)
        #pragma unroll
        for (int j = 0; j < 4; ++j) oacc[dt][j] *= sf;
      m_run = nm;
      mc = nm * SC;
      first = false;
    }
    // exp + pack
    unsigned pk0[4], pk1[4];
    #pragma unroll
    for (int tl = 0; tl < 4; ++tl) {
      float e0 = __builtin_amdgcn_exp2f(fmaf(st[tl][0], SC, -mc));
      float e1 = __builtin_amdgcn_exp2f(fmaf(st[tl][1], SC, -mc));
      float e2 = __builtin_amdgcn_exp2f(fmaf(st[tl][2], SC, -mc));
      float e3 = __builtin_amdgcn_exp2f(fmaf(st[tl][3], SC, -mc));
      ssum += (e0 + e1) + (e2 + e3);
      pk0[tl] = (unsigned)bfbits(e0) | ((unsigned)bfbits(e1) << 16);
      pk1[tl] = (unsigned)bfbits(e2) | ((unsigned)bfbits(e3) << 16);
    }
    // PV: 2 k-steps (32 keys each) of O^T = V^T @ P^T
    #pragma unroll
    for (int ksl = 0; ksl < 2; ++ksl) {
      int lt0 = 2 * ksl, lt1 = 2 * ksl + 1;
      unsigned a0 = __shfl(pk0[lt0], src0), b0 = __shfl(pk0[lt1], src0);
      unsigned a1 = __shfl(pk1[lt0], src0), b1 = __shfl(pk1[lt1], src0);
      unsigned a2 = __shfl(pk0[lt0], src1), b2 = __shfl(pk0[lt1], src1);
      unsigned a3 = __shfl(pk1[lt0], src1), b3 = __shfl(pk1[lt1], src1);
      u32x4 pw;
      pw[0] = hi ? b0 : a0; pw[1] = hi ? b1 : a1;
      pw[2] = hi ? b2 : a2; pw[3] = hi ? b3 : a3;
      bf16x8 pf = __builtin_bit_cast(bf16x8, pw);
      #pragma unroll
      for (int dt = 0; dt < 2; ++dt) {
        int d = 16 * dt + q16;
        bf16x8 vf = *(const bf16x8*)(cur + 4096 + ((d * 128 + 64 * ksl + 16 * g) ^ (((d >> 1) & 7) << 4)));
        oacc[dt] = __builtin_amdgcn_mfma_f32_16x16x32_bf16(vf, pf, oacc[dt], 0, 0, 0);
      }
    }

    // T14 write-late: LDS writes for chunk c+1 into the other buffer
    if (c < 6) {
      char* nxt = sm + ((c + 1) & 1) * ABUF;
      *(u32x4*)(nxt + ((tid * 16) ^ (((tid >> 2) & 7) << 4))) = kreg;
      u32x2 lo2, hi2;
      lo2[0] = (vr0 & 0xffffu) | (vr1 << 16);  lo2[1] = (vr2 & 0xffffu) | (vr3 << 16);
      hi2[0] = (vr0 >> 16) | (vr1 & 0xffff0000u); hi2[1] = (vr2 >> 16) | (vr3 & 0xffff0000u);
      unsigned swz = (unsigned)((vdp & 7) << 4);
      int byte0 = vdp * 256 + vko * 8;
      *(u32x2*)(nxt + 4096 + (byte0 ^ swz)) = lo2;
      *(u32x2*)(nxt + 4096 + ((byte0 + 128) ^ swz)) = hi2;
      __syncthreads();
    }
  }

  // ---- normalize + store: lane(q16,g) holds O^T[16dt+4g+j][q16] ----
  ssum += __shfl_xor(ssum, 16);
  ssum += __shfl_xor(ssum, 32);
  float inv = 1.0f / ssum;
  size_t orow = (base + n * 64 + w * 16 + q16) * 256 + hh * 32;
  #pragma unroll
  for (int dt = 0; dt < 2; ++dt) {
    u32x2 pk;
    pk[0] = (unsigned)bfbits(oacc[dt][0] * inv) | ((unsigned)bfbits(oacc[dt][1] * inv) << 16);
    pk[1] = (unsigned)bfbits(oacc[dt][2] * inv) | ((unsigned)bfbits(oacc[dt][3] * inv) << 16);
    *(u32x2*)(o + orow + 16 * dt + 4 * g) = pk;
  }
}

// ---------------- launch ----------------
extern "C" void kernel_launch(void* const* d_in, const int* in_sizes, int n_in,
                              void* d_out, int out_size, void* d_ws, size_t ws_size,
                              hipStream_t stream) {
  const int*   ids      = (const int*)d_in[0];
  const int*   rand_idx = (const int*)d_in[1];
  const float* emb      = (const float*)d_in[2];
  const float* ln1      = (const float*)d_in[3];
  const float* wq       = (const float*)d_in[4];
  const float* wk       = (const float*)d_in[5];
  const float* wv       = (const float*)d_in[6];
  const float* wo       = (const float*)d_in[7];
  const float* ln2      = (const float*)d_in[8];
  const float* w1       = (const float*)d_in[9];
  const float* w2       = (const float*)d_in[10];
  const float* fln      = (const float*)d_in[11];
  float* out = (float*)d_out;

  char* ws = (char*)d_ws;
  float*  x    = (float*)ws;                       // 16,777,216 B
  __bf16* h    = (__bf16*)(ws + 16777216);         //  8,388,608 B
  __bf16* qkv  = (__bf16*)(ws + 25165824);         // 25,165,824 B
  __bf16* obuf = (__bf16*)(ws + 50331648);         //  8,388,608 B
  __bf16* g    = qkv;                              // reuses qkv+obuf, both dead by FFN
  __bf16* wbase = (__bf16*)(ws + 58720256);        //  3,145,728 B

  transpose_all<<<6144, 256, 0, stream>>>(wq, wk, wv, wo, w1, w2, wbase);
  embed_k<<<4096, 256, 0, stream>>>(ids, emb, x);

  for (int l = 0; l < 2; ++l) {
    __bf16* qkvT = wbase + (size_t)l * 786432;
    __bf16* woT  = qkvT + 196608;
    __bf16* w1T  = woT + 65536;
    __bf16* w2T  = w1T + 262144;

    rmsnorm_k<__bf16><<<4096, 256, 0, stream>>>(x, ln1 + (size_t)l * 256, h);
    gemm_bt<128, false, false, true><<<dim3(128, 6), 256, 0, stream>>>(h, qkvT, qkv, nullptr, 256, 768);
    attn_k<<<2048, 256, ATTN_LDS, stream>>>(qkv, rand_idx, obuf);
    gemm_bt<64, true, false, false><<<dim3(256, 2), 256, 0, stream>>>(obuf, woT, nullptr, x, 256, 256);
    rmsnorm_k<__bf16><<<4096, 256, 0, stream>>>(x, ln2 + (size_t)l * 256, h);
    gemm_bt<128, false, true, true><<<dim3(128, 8), 256, 0, stream>>>(h, w1T, g, nullptr, 256, 1024);
    gemm_bt<64, true, false, false><<<dim3(256, 2), 256, 0, stream>>>(g, w2T, nullptr, x, 1024, 256);
  }

  rmsnorm_k<float><<<4096, 256, 0, stream>>>(x, fln, out);
}